// Round 2
// baseline (200.117 us; speedup 1.0000x reference)
//
#include <hip/hip_runtime.h>

// ---------------------------------------------------------------------------
// AttentionOT  (Nq=64, M=16, B=8, K=256, C=512)
//   Front (error-critical, feeds exp(20*sim)): bf16x3 split MFMA (Markidis),
//     operands PRE-SPLIT by a memory-bound prep pass.
//   Back half: plain bf16 MFMA, weights precast.
//   Sinkhorn (round 6): launch_bounds(256,2), permlane16/32 butterflies,
//     fixed-point early exit.  (verified round 6: 49us -> out of top-5)
//   qkv GEMM (round 7): 128x128 -> 64x128 tiles. Old grid was 384 blocks on
//     256 CUs (1.5/CU, 1 wave/SIMD, Occupancy 12.7%, MfmaUtil 15.7% -> pure
//     latency-bound). New grid 768 blocks = 3/CU, LDS 30KB, grid ordered so
//     consecutive blocks share the A-tile (L2 locality), launch_bounds(256,3).
//   7 dispatches: prep -> qkv -> rownorm -> sim -> sinkhorn -> T@V -> proj.
// ---------------------------------------------------------------------------

typedef short   short8  __attribute__((ext_vector_type(8)));
typedef float   floatx4 __attribute__((ext_vector_type(4)));
typedef unsigned int uint2e __attribute__((ext_vector_type(2)));

static __device__ __forceinline__ float fastrcp(float x) {
    return __builtin_amdgcn_rcpf(x);
}
static __device__ __forceinline__ unsigned short f2bf(float f) {
    union { float f; unsigned u; } c; c.f = f;
    unsigned r = c.u + 0x7FFF + ((c.u >> 16) & 1);   // RNE
    return (unsigned short)(r >> 16);
}
static __device__ __forceinline__ float bf2f(unsigned short h) {
    union { unsigned u; float f; } c; c.u = (unsigned)h << 16;
    return c.f;
}

// Cross-lane butterfly adds via gfx950 permlane16/32_swap (full-rate VALU,
// vs ~120cyc ds_bpermute for shfl_xor). With both operands equal, x+y equals
// s + shfl_xor(s, 16) (resp. 32) on every lane.
#if __has_builtin(__builtin_amdgcn_permlane16_swap)
static __device__ __forceinline__ float xadd16(float s) {
    uint2e r = __builtin_amdgcn_permlane16_swap(
        __float_as_uint(s), __float_as_uint(s), false, false);
    return __uint_as_float(r.x) + __uint_as_float(r.y);
}
#else
static __device__ __forceinline__ float xadd16(float s) {
    return s + __shfl_xor(s, 16, 64);
}
#endif
#if __has_builtin(__builtin_amdgcn_permlane32_swap)
static __device__ __forceinline__ float xadd32(float s) {
    uint2e r = __builtin_amdgcn_permlane32_swap(
        __float_as_uint(s), __float_as_uint(s), false, false);
    return __uint_as_float(r.x) + __uint_as_float(r.y);
}
#else
static __device__ __forceinline__ float xadd32(float s) {
    return s + __shfl_xor(s, 32, 64);
}
#endif

#define RRI(x, C) __builtin_amdgcn_update_dpp(0, (x), (C), 0xf, 0xf, true)
#define RRF(x, C) __int_as_float(RRI(__float_as_int(x), (C)))
#define GATH16(d, s) do { d[0] = (s);                                        \
    d[1]  = RRF((s), 0x121); d[2]  = RRF((s), 0x122);                        \
    d[3]  = RRF((s), 0x123); d[4]  = RRF((s), 0x124);                        \
    d[5]  = RRF((s), 0x125); d[6]  = RRF((s), 0x126);                        \
    d[7]  = RRF((s), 0x127); d[8]  = RRF((s), 0x128);                        \
    d[9]  = RRF((s), 0x129); d[10] = RRF((s), 0x12a);                        \
    d[11] = RRF((s), 0x12b); d[12] = RRF((s), 0x12c);                        \
    d[13] = RRF((s), 0x12d); d[14] = RRF((s), 0x12e);                        \
    d[15] = RRF((s), 0x12f); } while (0)

// ---------------------------------------------------------------------------
// prep: fp32 -> bf16 split (xq,xk,Wq,Wk) / cast (xv,Wv,Wp).  One dispatch,
// one float4 per thread, memory-bound.
// ---------------------------------------------------------------------------
__global__ __launch_bounds__(256) void prep(
    const float* __restrict__ xq, const float* __restrict__ xk,
    const float* __restrict__ xv, const float* __restrict__ Wq,
    const float* __restrict__ Wk, const float* __restrict__ Wv,
    const float* __restrict__ Wp,
    unsigned short* __restrict__ xqh, unsigned short* __restrict__ xql,
    unsigned short* __restrict__ xkh, unsigned short* __restrict__ xkl,
    unsigned short* __restrict__ xvb,
    unsigned short* __restrict__ wqh, unsigned short* __restrict__ wql,
    unsigned short* __restrict__ wkh, unsigned short* __restrict__ wkl,
    unsigned short* __restrict__ wvb, unsigned short* __restrict__ wpb)
{
    const int b = blockIdx.x;
    const float* src; unsigned short *dh, *dl; long base;
    if (b < 4096)      { src = xq; dh = xqh; dl = xql;     base = (long)b * 256; }
    else if (b < 5120) { src = xk; dh = xkh; dl = xkl;     base = (long)(b - 4096) * 256; }
    else if (b < 6144) { src = xv; dh = xvb; dl = nullptr; base = (long)(b - 5120) * 256; }
    else if (b < 6400) { src = Wq; dh = wqh; dl = wql;     base = (long)(b - 6144) * 256; }
    else if (b < 6656) { src = Wk; dh = wkh; dl = wkl;     base = (long)(b - 6400) * 256; }
    else if (b < 6912) { src = Wv; dh = wvb; dl = nullptr; base = (long)(b - 6656) * 256; }
    else               { src = Wp; dh = wpb; dl = nullptr; base = (long)(b - 6912) * 256; }
    const long i = base + threadIdx.x;
    float4 v = ((const float4*)src)[i];
    ushort4 h;
    h.x = f2bf(v.x); h.y = f2bf(v.y); h.z = f2bf(v.z); h.w = f2bf(v.w);
    ((ushort4*)dh)[i] = h;
    if (dl) {
        ushort4 l;
        l.x = f2bf(v.x - bf2f(h.x)); l.y = f2bf(v.y - bf2f(h.y));
        l.z = f2bf(v.z - bf2f(h.z)); l.w = f2bf(v.w - bf2f(h.w));
        ((ushort4*)dl)[i] = l;
    }
}

// ---------------------------------------------------------------------------
// Fused q/k/v projection on PRECONVERTED bf16 operands.  64x128 tiles,
// BK=32, 768 blocks (3/CU).  blockIdx.y: 0..127 q (split3), 128..159 k
// (split3), 160..191 v (plain).  blockIdx.x = j0 slice (fast dim -> blocks
// sharing an A-tile are consecutive, L2-hot).
// Epilogues: q -> qh/ql permuted rows; k -> kh/kl; v -> vt[b][c][k'] via
// LDS transpose (coalesced 16B stores).
// ---------------------------------------------------------------------------
__global__ __launch_bounds__(256, 3) void gemm_qkv2(
    const unsigned short* __restrict__ xqh, const unsigned short* __restrict__ xql,
    const unsigned short* __restrict__ xkh, const unsigned short* __restrict__ xkl,
    const unsigned short* __restrict__ xvb,
    const unsigned short* __restrict__ wqh, const unsigned short* __restrict__ wql,
    const unsigned short* __restrict__ wkh, const unsigned short* __restrict__ wkl,
    const unsigned short* __restrict__ wvb,
    unsigned short* __restrict__ qh, unsigned short* __restrict__ ql,
    unsigned short* __restrict__ kh, unsigned short* __restrict__ kl,
    unsigned short* __restrict__ vt)
{
    __shared__ __align__(16) short LB[15360];          // 30 KB
    short (*Ash)[40] = (short(*)[40])(LB);             // 64 x 40
    short (*Asl)[40] = (short(*)[40])(LB + 2560);      // 64 x 40
    short (*Bsh)[40] = (short(*)[40])(LB + 5120);      // 128 x 40
    short (*Bsl)[40] = (short(*)[40])(LB + 10240);     // 128 x 40

    const int bt = blockIdx.y;                         // tile id 0..191
    const unsigned short *Ah, *Al, *Bh, *Bl;
    int seg, arow0;
    if (bt < 128)      { Ah = xqh; Al = xql; Bh = wqh; Bl = wql; arow0 = bt * 64;         seg = 0; }
    else if (bt < 160) { Ah = xkh; Al = xkl; Bh = wkh; Bl = wkl; arow0 = (bt - 128) * 64; seg = 1; }
    else               { Ah = xvb; Al = xvb; Bh = wvb; Bl = wvb; arow0 = (bt - 160) * 64; seg = 2; }
    const bool split = (seg != 2);

    const int tid  = threadIdx.x;
    const int lane = tid & 63, wv = tid >> 6;
    const int wc = wv * 32;                            // wave col slice
    const int j0 = blockIdx.x * 128;

    floatx4 acc[4][2];
#pragma unroll
    for (int i = 0; i < 4; i++)
#pragma unroll
        for (int j = 0; j < 2; j++) acc[i][j] = {0.f, 0.f, 0.f, 0.f};

    const int sr = tid >> 2, sch = (tid & 3) * 8;
    const int fr = lane & 15, fq = (lane >> 4) * 8;

    for (int k0 = 0; k0 < 512; k0 += 32) {
        {   // stage A: 64 rows, one short8 per thread per array
            const long ao = (long)(arow0 + sr) * 512 + k0 + sch;
            *(short8*)&Ash[sr][sch] = *(const short8*)(Ah + ao);
            if (split) *(short8*)&Asl[sr][sch] = *(const short8*)(Al + ao);
        }
#pragma unroll
        for (int p = 0; p < 2; p++) {                  // stage B: 128 rows
            const int r = sr + p * 64;
            const long bo = (long)(j0 + r) * 512 + k0 + sch;
            *(short8*)&Bsh[r][sch] = *(const short8*)(Bh + bo);
            if (split) *(short8*)&Bsl[r][sch] = *(const short8*)(Bl + bo);
        }
        __syncthreads();
        short8 ah[4], bh[2];
#pragma unroll
        for (int i = 0; i < 4; i++) ah[i] = *(const short8*)&Ash[i * 16 + fr][fq];
#pragma unroll
        for (int j = 0; j < 2; j++) bh[j] = *(const short8*)&Bsh[wc + j * 16 + fr][fq];
        if (split) {
            short8 al[4], bl[2];
#pragma unroll
            for (int i = 0; i < 4; i++) al[i] = *(const short8*)&Asl[i * 16 + fr][fq];
#pragma unroll
            for (int j = 0; j < 2; j++) bl[j] = *(const short8*)&Bsl[wc + j * 16 + fr][fq];
#pragma unroll
            for (int i = 0; i < 4; i++)
#pragma unroll
                for (int j = 0; j < 2; j++) {
                    acc[i][j] = __builtin_amdgcn_mfma_f32_16x16x32_bf16(ah[i], bh[j], acc[i][j], 0, 0, 0);
                    acc[i][j] = __builtin_amdgcn_mfma_f32_16x16x32_bf16(ah[i], bl[j], acc[i][j], 0, 0, 0);
                    acc[i][j] = __builtin_amdgcn_mfma_f32_16x16x32_bf16(al[i], bh[j], acc[i][j], 0, 0, 0);
                }
        } else {
#pragma unroll
            for (int i = 0; i < 4; i++)
#pragma unroll
                for (int j = 0; j < 2; j++)
                    acc[i][j] = __builtin_amdgcn_mfma_f32_16x16x32_bf16(ah[i], bh[j], acc[i][j], 0, 0, 0);
        }
        __syncthreads();
    }

    const int cr = (lane >> 4) * 4, cc = lane & 15;
    if (seg == 2) {
        // LDS transpose: S2[c_local][k'_local], rows padded to 72 shorts
        short (*S2)[72] = (short(*)[72])LB;            // 128 x 72 = 18 KB
#pragma unroll
        for (int i = 0; i < 4; i++)
#pragma unroll
            for (int j = 0; j < 2; j++)
#pragma unroll
                for (int r = 0; r < 4; r++)
                    S2[wc + j * 16 + cc][i * 16 + cr + r] =
                        (short)f2bf(acc[i][j][r]);
        __syncthreads();
        const int orow = tid >> 1;            // c_local 0..127
        const int os   = (tid & 1) * 32;      // k'_local chunk
        unsigned short* dst = vt + (long)(arow0 >> 8) * 131072
                            + (long)(j0 + orow) * 256 + (arow0 & 255) + os;
#pragma unroll
        for (int c8 = 0; c8 < 4; c8++)
            *(short8*)(dst + c8 * 8) = *(const short8*)&S2[orow][os + c8 * 8];
    } else {
#pragma unroll
        for (int i = 0; i < 4; i++)
#pragma unroll
            for (int j = 0; j < 2; j++) {
                const int gj = j0 + wc + j * 16 + cc;
#pragma unroll
                for (int r = 0; r < 4; r++) {
                    const int gi = arow0 + i * 16 + cr + r;
                    const float v = acc[i][j][r];
                    const unsigned short h = f2bf(v);
                    const unsigned short lo = f2bf(v - bf2f(h));
                    if (seg == 0) {
                        const long orow = (long)((gi & 7) * 1024 + ((gi >> 3) & 15) * 64 + (gi >> 7));
                        qh[orow * 512 + gj] = h;
                        ql[orow * 512 + gj] = lo;
                    } else {
                        kh[(long)gi * 512 + gj] = h;
                        kl[(long)gi * 512 + gj] = lo;
                    }
                }
            }
    }
}

// ---------------------------------------------------------------------------
// sim GEMM, 64x64 tiles (512 blocks), bf16x3 on split pairs, epilogue scale
// rs_k[i]*rs_q[j].
// ---------------------------------------------------------------------------
__global__ __launch_bounds__(256) void gemm_sim64(
    const short* __restrict__ Ah, const short* __restrict__ Al,
    const short* __restrict__ Bh, const short* __restrict__ Bl,
    float* __restrict__ Out, const float* __restrict__ rs)
{
    const int z = blockIdx.z;
    Ah += (long)z * 131072;  Al += (long)z * 131072;
    Bh += (long)z * 524288;  Bl += (long)z * 524288;
    Out += (long)z * 262144;
    const float* rsq = rs + (long)z * 1024;
    const float* rsk = rs + 8192 + (long)z * 256;

    __shared__ __align__(16) short Ash[64][40];
    __shared__ __align__(16) short Asl[64][40];
    __shared__ __align__(16) short Bsh[64][40];
    __shared__ __align__(16) short Bsl[64][40];

    const int tid  = threadIdx.x;
    const int lane = tid & 63, wv = tid >> 6;
    const int wr = (wv >> 1) * 32, wc = (wv & 1) * 32;
    const int i0 = blockIdx.x * 64, j0 = blockIdx.y * 64;

    floatx4 acc[2][2];
#pragma unroll
    for (int i = 0; i < 2; i++)
#pragma unroll
        for (int j = 0; j < 2; j++) acc[i][j] = {0.f, 0.f, 0.f, 0.f};

    const int sr = tid >> 2, sch = (tid & 3) * 8;
    const int fr = lane & 15, fq = (lane >> 4) * 8;

    for (int k0 = 0; k0 < 512; k0 += 32) {
        const long ao = (long)(i0 + sr) * 512 + k0 + sch;
        const long bo = (long)(j0 + sr) * 512 + k0 + sch;
        *(short8*)&Ash[sr][sch] = *(const short8*)(Ah + ao);
        *(short8*)&Asl[sr][sch] = *(const short8*)(Al + ao);
        *(short8*)&Bsh[sr][sch] = *(const short8*)(Bh + bo);
        *(short8*)&Bsl[sr][sch] = *(const short8*)(Bl + bo);
        __syncthreads();
        short8 ah[2], al[2], bh[2], bl[2];
#pragma unroll
        for (int i = 0; i < 2; i++) {
            ah[i] = *(const short8*)&Ash[wr + i * 16 + fr][fq];
            al[i] = *(const short8*)&Asl[wr + i * 16 + fr][fq];
        }
#pragma unroll
        for (int j = 0; j < 2; j++) {
            bh[j] = *(const short8*)&Bsh[wc + j * 16 + fr][fq];
            bl[j] = *(const short8*)&Bsl[wc + j * 16 + fr][fq];
        }
#pragma unroll
        for (int i = 0; i < 2; i++)
#pragma unroll
            for (int j = 0; j < 2; j++) {
                acc[i][j] = __builtin_amdgcn_mfma_f32_16x16x32_bf16(ah[i], bh[j], acc[i][j], 0, 0, 0);
                acc[i][j] = __builtin_amdgcn_mfma_f32_16x16x32_bf16(ah[i], bl[j], acc[i][j], 0, 0, 0);
                acc[i][j] = __builtin_amdgcn_mfma_f32_16x16x32_bf16(al[i], bh[j], acc[i][j], 0, 0, 0);
            }
        __syncthreads();
    }

    const int cr = (lane >> 4) * 4, cc = lane & 15;
#pragma unroll
    for (int i = 0; i < 2; i++)
#pragma unroll
        for (int j = 0; j < 2; j++) {
            const int gj = j0 + wc + j * 16 + cc;
            const float sq = rsq[gj];
#pragma unroll
            for (int r = 0; r < 4; r++) {
                const int gi = i0 + wr + i * 16 + cr + r;
                Out[(long)gi * 1024 + gj] = acc[i][j][r] * rsk[gi] * sq;
            }
        }
}

// ---------------------------------------------------------------------------
// Plain bf16 MFMA GEMM (T@V and final proj), 128x128, BK=32, pure bf16.
// ---------------------------------------------------------------------------
template <bool BIAS, bool OPERM, bool OUT_BF16>
__global__ __launch_bounds__(256) void gemm_bf16(
    const short* __restrict__ A, const short* __restrict__ B,
    const float* __restrict__ bias, void* __restrict__ OutV,
    int Kdim, int lda, int ldb, int ldo, long sA, long sB, long sO)
{
    __shared__ __align__(16) short As[128][40];
    __shared__ __align__(16) short Bs[128][40];

    const int tid  = threadIdx.x;
    const int lane = tid & 63, wv = tid >> 6;
    const int wr = (wv >> 1) * 64, wc = (wv & 1) * 64;
    const int i0 = blockIdx.x * 128, j0 = blockIdx.y * 128;

    floatx4 acc[4][4];
#pragma unroll
    for (int i = 0; i < 4; i++)
#pragma unroll
        for (int j = 0; j < 4; j++) acc[i][j] = {0.f, 0.f, 0.f, 0.f};

    const int sr = tid >> 2, sk = (tid & 3) * 8;
    const int fr = lane & 15, fq = (lane >> 4) * 8;
    const short* pa = A + (long)blockIdx.z * sA;
    const short* pb = B + (long)blockIdx.z * sB;

    for (int k0 = 0; k0 < Kdim; k0 += 32) {
#pragma unroll
        for (int p = 0; p < 2; p++) {
            *(short8*)&As[sr + p * 64][sk] =
                *(const short8*)(pa + (long)(i0 + sr + p * 64) * lda + k0 + sk);
            *(short8*)&Bs[sr + p * 64][sk] =
                *(const short8*)(pb + (long)(j0 + sr + p * 64) * ldb + k0 + sk);
        }
        __syncthreads();
        short8 af[4], bf[4];
#pragma unroll
        for (int i = 0; i < 4; i++) af[i] = *(const short8*)&As[wr + i * 16 + fr][fq];
#pragma unroll
        for (int j = 0; j < 4; j++) bf[j] = *(const short8*)&Bs[wc + j * 16 + fr][fq];
#pragma unroll
        for (int i = 0; i < 4; i++)
#pragma unroll
            for (int j = 0; j < 4; j++)
                acc[i][j] = __builtin_amdgcn_mfma_f32_16x16x32_bf16(af[i], bf[j], acc[i][j], 0, 0, 0);
        __syncthreads();
    }

    float* Of = nullptr; unsigned short* Ob = nullptr;
    if constexpr (OUT_BF16) Ob = (unsigned short*)OutV + (long)blockIdx.z * sO;
    else                    Of = (float*)OutV + (long)blockIdx.z * sO;
    const int cr = (lane >> 4) * 4, cc = lane & 15;
#pragma unroll
    for (int i = 0; i < 4; i++) {
#pragma unroll
        for (int j = 0; j < 4; j++) {
            const int gj = j0 + wc + j * 16 + cc;
            float bb = 0.0f;
            if constexpr (BIAS) bb = bias[gj];
#pragma unroll
            for (int r = 0; r < 4; r++) {
                const int gi = i0 + wr + i * 16 + cr + r;
                float v = acc[i][j][r] + bb;
                long idx;
                if constexpr (OPERM)
                    idx = (long)((gi & 63) * 128 + ((gi >> 6) & 15) * 8 + (gi >> 10)) * ldo + gj;
                else
                    idx = (long)gi * ldo + gj;
                if constexpr (OUT_BF16) Ob[idx] = f2bf(v);
                else                    Of[idx] = v;
            }
        }
    }
}

// ---------------------------------------------------------------------------
// Row reciprocal-norms from split pairs: rows 0..8191 q, 8192..10239 k.
// ---------------------------------------------------------------------------
__global__ __launch_bounds__(256) void rownorm(
    const unsigned short* __restrict__ qh, const unsigned short* __restrict__ ql,
    const unsigned short* __restrict__ kh, const unsigned short* __restrict__ kl,
    float* __restrict__ rs)
{
    const int row  = blockIdx.x * 4 + (threadIdx.x >> 6);
    const int lane = threadIdx.x & 63;
    const unsigned short *ph, *pl;
    long r;
    if (row < 8192) { ph = qh; pl = ql; r = row; }
    else            { ph = kh; pl = kl; r = row - 8192; }
    const long o = r * 512 + lane * 8;
    ushort4 h0 = *(const ushort4*)(ph + o), h1 = *(const ushort4*)(ph + o + 4);
    ushort4 l0 = *(const ushort4*)(pl + o), l1 = *(const ushort4*)(pl + o + 4);
    float ss = 0.0f;
    const unsigned short hv[8] = {h0.x, h0.y, h0.z, h0.w, h1.x, h1.y, h1.z, h1.w};
    const unsigned short lv[8] = {l0.x, l0.y, l0.z, l0.w, l1.x, l1.y, l1.z, l1.w};
#pragma unroll
    for (int i = 0; i < 8; i++) {
        const float v = bf2f(hv[i]) + bf2f(lv[i]);
        ss = fmaf(v, v, ss);
    }
#pragma unroll
    for (int off = 32; off; off >>= 1) ss += __shfl_xor(ss, off, 64);
    if (lane == 0) rs[row] = 1.0f / fmaxf(sqrtf(ss), 1e-12f);
}

// ---------------------------------------------------------------------------
// Sinkhorn, rotated dual layouts + DPP + permlane butterflies + early exit.
// ---------------------------------------------------------------------------
__global__ __launch_bounds__(256, 2) void sinkhorn5(
    const float* __restrict__ sim, float* __restrict__ score,
    unsigned short* __restrict__ Tt)
{
    const int lane = threadIdx.x & 63;
    const int bk   = blockIdx.x * 4 + (threadIdx.x >> 6);
    const float* S = sim + (long)bk * 1024;
    const int m = lane & 15, g = lane >> 4;

    int idx[16];
    idx[0] = m;
    idx[1]  = RRI(m, 0x121); idx[2]  = RRI(m, 0x122); idx[3]  = RRI(m, 0x123);
    idx[4]  = RRI(m, 0x124); idx[5]  = RRI(m, 0x125); idx[6]  = RRI(m, 0x126);
    idx[7]  = RRI(m, 0x127); idx[8]  = RRI(m, 0x128); idx[9]  = RRI(m, 0x129);
    idx[10] = RRI(m, 0x12a); idx[11] = RRI(m, 0x12b); idx[12] = RRI(m, 0x12c);
    idx[13] = RRI(m, 0x12d); idx[14] = RRI(m, 0x12e); idx[15] = RRI(m, 0x12f);

    float K1[16], K2R[16], sv[16];
#pragma unroll
    for (int j = 0; j < 16; j++) {
        K1[j] = __expf((S[m * 64 + g * 16 + idx[j]] - 1.0f) * 20.0f);
        const float s_ = S[idx[j] * 64 + lane];
        sv[j]  = s_;
        K2R[j] = __expf((s_ - 1.0f) * 20.0f);
    }

    const float muP = 0.0625f + 1e-8f;
    const float nuP = 0.015625f + 1e-8f;
    float b = 1.0f;
    float aB[16], bB[16];
#pragma unroll
    for (int j = 0; j < 16; j++) bB[j] = 1.0f;

#pragma unroll 1
    for (int it = 0; it < 100; it++) {
        float s0 = 0, s1 = 0, s2 = 0, s3 = 0;
#pragma unroll
        for (int j = 0; j < 4; j++) {
            s0 = fmaf(K1[j],      bB[j],      s0);
            s1 = fmaf(K1[4 + j],  bB[4 + j],  s1);
            s2 = fmaf(K1[8 + j],  bB[8 + j],  s2);
            s3 = fmaf(K1[12 + j], bB[12 + j], s3);
        }
        float s = (s0 + s1) + (s2 + s3);
        s = xadd16(s);
        s = xadd32(s);
        const float a = muP * fastrcp(s);
        GATH16(aB, a);
        float t0 = 0, t1 = 0, t2 = 0, t3 = 0;
#pragma unroll
        for (int j = 0; j < 4; j++) {
            t0 = fmaf(K2R[j],      aB[j],      t0);
            t1 = fmaf(K2R[4 + j],  aB[4 + j],  t1);
            t2 = fmaf(K2R[8 + j],  aB[8 + j],  t2);
            t3 = fmaf(K2R[12 + j], aB[12 + j], t3);
        }
        const float bp_ = b;
        b = nuP * fastrcp((t0 + t1) + (t2 + t3));
        GATH16(bB, b);
        const int conv = __builtin_fabsf(b - bp_) <= 1e-5f * __builtin_fabsf(b);
        if (__all(conv)) break;
    }

    float* Sc = score + (long)bk * 1024;
    unsigned short* Tp = Tt + (long)(bk >> 8) * 262144 + (bk & 255);
#pragma unroll
    for (int j = 0; j < 16; j++) {
        const int row = idx[j];
        const float Tv = aB[j] * K2R[j] * b;
        Sc[row * 64 + lane] = 1024.0f * sv[j] * Tv;
        Tp[(long)(row * 64 + lane) * 256] = f2bf(Tv);
    }
}

extern "C" void kernel_launch(void* const* d_in, const int* in_sizes, int n_in,
                              void* d_out, int out_size, void* d_ws, size_t ws_size,
                              hipStream_t stream)
{
    (void)in_sizes; (void)n_in; (void)out_size; (void)ws_size;
    const float* xq = (const float*)d_in[0];
    const float* xk = (const float*)d_in[1];
    const float* xv = (const float*)d_in[2];
    const float* Wq = (const float*)d_in[3];
    const float* Wk = (const float*)d_in[4];
    const float* Wv = (const float*)d_in[5];
    const float* Wp = (const float*)d_in[6];
    const float* bp = (const float*)d_in[7];

    float* out_x     = (float*)d_out;           // (Nq,M,B,C) = 8192 x 512
    float* out_score = out_x + 8192L * 512;     // (B,K,M,Nq) = 2048 x 1024

    // workspace (47.1 MB of the proven 48 MB); regions reused across phases
    char* W = (char*)d_ws;
    const long MB = 1 << 20;
    unsigned short* qh   = (unsigned short*)(W + 0);        // 8MB [b][mn][c]
    unsigned short* ql   = (unsigned short*)(W + 8 * MB);   // 8MB
    unsigned short* xq_h = (unsigned short*)(W + 16 * MB);  // 8MB, dead after qkv
    float*          simb = (float*)(W + 16 * MB);           // 8MB (reuse)
    unsigned short* xq_l = (unsigned short*)(W + 24 * MB);  // 8MB, dead after qkv
    unsigned short* xpre = (unsigned short*)(W + 24 * MB);  // 8MB (reuse)
    unsigned short* xk_h = (unsigned short*)(W + 32 * MB);  // 2MB, dead after qkv
    unsigned short* xk_l = (unsigned short*)(W + 34 * MB);  // 2MB
    unsigned short* Tt   = (unsigned short*)(W + 32 * MB);  // 4MB (reuse)
    unsigned short* xv_b = (unsigned short*)(W + 36 * MB);  // 2MB
    unsigned short* kh   = (unsigned short*)(W + 38 * MB);  // 2MB [b][k'][c]
    unsigned short* kl   = (unsigned short*)(W + 40 * MB);  // 2MB
    unsigned short* vt   = (unsigned short*)(W + 42 * MB);  // 2MB [b][c][k']
    unsigned short* wqh  = (unsigned short*)(W + 44 * MB);
    unsigned short* wql  = (unsigned short*)(W + 44 * MB + 1 * 524288);
    unsigned short* wkh  = (unsigned short*)(W + 44 * MB + 2 * 524288);
    unsigned short* wkl  = (unsigned short*)(W + 44 * MB + 3 * 524288);
    unsigned short* wvb  = (unsigned short*)(W + 44 * MB + 4 * 524288);
    unsigned short* wpb  = (unsigned short*)(W + 44 * MB + 5 * 524288);
    float*          rs   = (float*)(W + 47 * MB);           // 40KB

    const dim3 blk(256);

    // 1: precast/split all fp32 operands (memory-bound, one dispatch)
    prep<<<7168, blk, 0, stream>>>(xq, xk, xv, Wq, Wk, Wv, Wp,
                                   xq_h, xq_l, xk_h, xk_l, xv_b,
                                   wqh, wql, wkh, wkl, wvb, wpb);

    // 2: fused q/k/v projections on bf16 operands (64x128 tiles, 768 blocks)
    gemm_qkv2<<<dim3(4, 192), blk, 0, stream>>>(
        xq_h, xq_l, xk_h, xk_l, xv_b, wqh, wql, wkh, wkl, wvb,
        qh, ql, kh, kl, vt);

    // 3: reciprocal row norms
    rownorm<<<2560, blk, 0, stream>>>(qh, ql, kh, kl, rs);

    // 4: sim[b][k'][mn] = (k.q) * rs_k * rs_q
    gemm_sim64<<<dim3(4, 16, 8), blk, 0, stream>>>(
        (const short*)kh, (const short*)kl, (const short*)qh, (const short*)ql,
        simb, rs);

    // 5: Sinkhorn -> score (out) + T bf16 [b][mn][k']
    sinkhorn5<<<512, blk, 0, stream>>>(simb, out_score, Tt);

    // 6: xpre[b][mn][c] = sum_k' T[b][mn][k'] * v[b][k'][c]
    gemm_bf16<false, false, true><<<dim3(8, 4, 8), blk, 0, stream>>>(
        (const short*)Tt, (const short*)vt, nullptr, xpre,
        256, 256, 256, 512, 262144, 131072, 524288);

    // 7: x = xpre @ Wp^T + bp, rows (b,mn)->(n,m,b), fp32 out
    gemm_bf16<true, true, false><<<dim3(64, 4), blk, 0, stream>>>(
        (const short*)xpre, (const short*)wpb, bp, out_x,
        512, 512, 512, 512, 0, 0, 0);
}

// Round 3
// 196.308 us; speedup vs baseline: 1.0194x; 1.0194x over previous
//
#include <hip/hip_runtime.h>

// ---------------------------------------------------------------------------
// AttentionOT  (Nq=64, M=16, B=8, K=256, C=512)
//   Front (error-critical, feeds exp(20*sim)): bf16x3 split MFMA (Markidis),
//     operands PRE-SPLIT by a memory-bound prep pass.
//   Back half: plain bf16 MFMA, weights precast.
//   Sinkhorn (round 6): launch_bounds(256,2), permlane16/32 butterflies,
//     fixed-point early exit.  (verified: 49us -> out of top-5)
//   qkv GEMM (round 8): back to 128x128 / 384 blocks (round-7's 64x128 retile
//     REGRESSED: MfmaUtil 13.6%, FETCH 2.2x — occupancy wasn't the bottleneck,
//     the 2-barrier-per-K-step serial pipeline was). Now: LDS double-buffer
//     (2x40KB), prefetch next K-tile's global loads BEFORE the MFMA block,
//     ds_write to the other buffer after — ONE barrier per K-step, HBM
//     latency hidden under MFMA. launch_bounds(256,2) for full VGPR budget.
//   7 dispatches: prep -> qkv -> rownorm -> sim -> sinkhorn -> T@V -> proj.
// ---------------------------------------------------------------------------

typedef short   short8  __attribute__((ext_vector_type(8)));
typedef float   floatx4 __attribute__((ext_vector_type(4)));
typedef unsigned int uint2e __attribute__((ext_vector_type(2)));

static __device__ __forceinline__ float fastrcp(float x) {
    return __builtin_amdgcn_rcpf(x);
}
static __device__ __forceinline__ unsigned short f2bf(float f) {
    union { float f; unsigned u; } c; c.f = f;
    unsigned r = c.u + 0x7FFF + ((c.u >> 16) & 1);   // RNE
    return (unsigned short)(r >> 16);
}
static __device__ __forceinline__ float bf2f(unsigned short h) {
    union { unsigned u; float f; } c; c.u = (unsigned)h << 16;
    return c.f;
}

// Cross-lane butterfly adds via gfx950 permlane16/32_swap (full-rate VALU,
// vs ~120cyc ds_bpermute for shfl_xor). With both operands equal, x+y equals
// s + shfl_xor(s, 16) (resp. 32) on every lane.
#if __has_builtin(__builtin_amdgcn_permlane16_swap)
static __device__ __forceinline__ float xadd16(float s) {
    uint2e r = __builtin_amdgcn_permlane16_swap(
        __float_as_uint(s), __float_as_uint(s), false, false);
    return __uint_as_float(r.x) + __uint_as_float(r.y);
}
#else
static __device__ __forceinline__ float xadd16(float s) {
    return s + __shfl_xor(s, 16, 64);
}
#endif
#if __has_builtin(__builtin_amdgcn_permlane32_swap)
static __device__ __forceinline__ float xadd32(float s) {
    uint2e r = __builtin_amdgcn_permlane32_swap(
        __float_as_uint(s), __float_as_uint(s), false, false);
    return __uint_as_float(r.x) + __uint_as_float(r.y);
}
#else
static __device__ __forceinline__ float xadd32(float s) {
    return s + __shfl_xor(s, 32, 64);
}
#endif

#define RRI(x, C) __builtin_amdgcn_update_dpp(0, (x), (C), 0xf, 0xf, true)
#define RRF(x, C) __int_as_float(RRI(__float_as_int(x), (C)))
#define GATH16(d, s) do { d[0] = (s);                                        \
    d[1]  = RRF((s), 0x121); d[2]  = RRF((s), 0x122);                        \
    d[3]  = RRF((s), 0x123); d[4]  = RRF((s), 0x124);                        \
    d[5]  = RRF((s), 0x125); d[6]  = RRF((s), 0x126);                        \
    d[7]  = RRF((s), 0x127); d[8]  = RRF((s), 0x128);                        \
    d[9]  = RRF((s), 0x129); d[10] = RRF((s), 0x12a);                        \
    d[11] = RRF((s), 0x12b); d[12] = RRF((s), 0x12c);                        \
    d[13] = RRF((s), 0x12d); d[14] = RRF((s), 0x12e);                        \
    d[15] = RRF((s), 0x12f); } while (0)

// ---------------------------------------------------------------------------
// prep: fp32 -> bf16 split (xq,xk,Wq,Wk) / cast (xv,Wv,Wp).  One dispatch,
// one float4 per thread, memory-bound.
// ---------------------------------------------------------------------------
__global__ __launch_bounds__(256) void prep(
    const float* __restrict__ xq, const float* __restrict__ xk,
    const float* __restrict__ xv, const float* __restrict__ Wq,
    const float* __restrict__ Wk, const float* __restrict__ Wv,
    const float* __restrict__ Wp,
    unsigned short* __restrict__ xqh, unsigned short* __restrict__ xql,
    unsigned short* __restrict__ xkh, unsigned short* __restrict__ xkl,
    unsigned short* __restrict__ xvb,
    unsigned short* __restrict__ wqh, unsigned short* __restrict__ wql,
    unsigned short* __restrict__ wkh, unsigned short* __restrict__ wkl,
    unsigned short* __restrict__ wvb, unsigned short* __restrict__ wpb)
{
    const int b = blockIdx.x;
    const float* src; unsigned short *dh, *dl; long base;
    if (b < 4096)      { src = xq; dh = xqh; dl = xql;     base = (long)b * 256; }
    else if (b < 5120) { src = xk; dh = xkh; dl = xkl;     base = (long)(b - 4096) * 256; }
    else if (b < 6144) { src = xv; dh = xvb; dl = nullptr; base = (long)(b - 5120) * 256; }
    else if (b < 6400) { src = Wq; dh = wqh; dl = wql;     base = (long)(b - 6144) * 256; }
    else if (b < 6656) { src = Wk; dh = wkh; dl = wkl;     base = (long)(b - 6400) * 256; }
    else if (b < 6912) { src = Wv; dh = wvb; dl = nullptr; base = (long)(b - 6656) * 256; }
    else               { src = Wp; dh = wpb; dl = nullptr; base = (long)(b - 6912) * 256; }
    const long i = base + threadIdx.x;
    float4 v = ((const float4*)src)[i];
    ushort4 h;
    h.x = f2bf(v.x); h.y = f2bf(v.y); h.z = f2bf(v.z); h.w = f2bf(v.w);
    ((ushort4*)dh)[i] = h;
    if (dl) {
        ushort4 l;
        l.x = f2bf(v.x - bf2f(h.x)); l.y = f2bf(v.y - bf2f(h.y));
        l.z = f2bf(v.z - bf2f(h.z)); l.w = f2bf(v.w - bf2f(h.w));
        ((ushort4*)dl)[i] = l;
    }
}

// ---------------------------------------------------------------------------
// Fused q/k/v projection on PRECONVERTED bf16 operands.  blockIdx.x:
// 0..63 q (split3), 64..79 k (split3), 80..95 v (plain).  128x128, BK=32.
// Round 8: LDS double-buffer + single barrier per K-step + early prefetch.
// Epilogues: q -> qh/ql permuted rows; k -> kh/kl; v -> vt[b][c][k'] via
// LDS transpose (coalesced 16B stores).
// ---------------------------------------------------------------------------
__global__ __launch_bounds__(256, 2) void gemm_qkv2(
    const unsigned short* __restrict__ xqh, const unsigned short* __restrict__ xql,
    const unsigned short* __restrict__ xkh, const unsigned short* __restrict__ xkl,
    const unsigned short* __restrict__ xvb,
    const unsigned short* __restrict__ wqh, const unsigned short* __restrict__ wql,
    const unsigned short* __restrict__ wkh, const unsigned short* __restrict__ wkl,
    const unsigned short* __restrict__ wvb,
    unsigned short* __restrict__ qh, unsigned short* __restrict__ ql,
    unsigned short* __restrict__ kh, unsigned short* __restrict__ kl,
    unsigned short* __restrict__ vt)
{
    // two staging buffers of 20480 shorts (40KB) each:
    //   +0 Ash[128][40], +5120 Asl[128][40], +10240 Bsh[128][40], +15360 Bsl
    __shared__ __align__(16) short LB[40960];          // 80 KB

    const int bx = blockIdx.x;
    const unsigned short *Ah, *Al, *Bh, *Bl;
    int seg, arow0;
    if (bx < 64)      { Ah = xqh; Al = xql; Bh = wqh; Bl = wql; arow0 = bx * 128;        seg = 0; }
    else if (bx < 80) { Ah = xkh; Al = xkl; Bh = wkh; Bl = wkl; arow0 = (bx - 64) * 128; seg = 1; }
    else              { Ah = xvb; Al = xvb; Bh = wvb; Bl = wvb; arow0 = (bx - 80) * 128; seg = 2; }
    const bool split = (seg != 2);

    const int tid  = threadIdx.x;
    const int lane = tid & 63, wv = tid >> 6;
    const int wr = (wv >> 1) * 64, wc = (wv & 1) * 64;
    const int j0 = blockIdx.y * 128;

    floatx4 acc[4][4];
#pragma unroll
    for (int i = 0; i < 4; i++)
#pragma unroll
        for (int j = 0; j < 4; j++) acc[i][j] = {0.f, 0.f, 0.f, 0.f};

    const int sr = tid >> 2, sch = (tid & 3) * 8;
    const int fr = lane & 15, fq = (lane >> 4) * 8;

    // prefetch registers (static-indexed; rule: no runtime-indexed reg arrays)
    short8 ra0, ra1, rb0, rb1, rla0, rla1, rlb0, rlb1;

#define QKV_LOADT(k0) do {                                                   \
        const long ao0 = (long)(arow0 + sr) * 512 + (k0) + sch;              \
        const long bo0 = (long)(j0 + sr) * 512 + (k0) + sch;                 \
        ra0 = *(const short8*)(Ah + ao0);                                    \
        ra1 = *(const short8*)(Ah + ao0 + 64 * 512);                         \
        rb0 = *(const short8*)(Bh + bo0);                                    \
        rb1 = *(const short8*)(Bh + bo0 + 64 * 512);                         \
        if (split) {                                                         \
            rla0 = *(const short8*)(Al + ao0);                               \
            rla1 = *(const short8*)(Al + ao0 + 64 * 512);                    \
            rlb0 = *(const short8*)(Bl + bo0);                               \
            rlb1 = *(const short8*)(Bl + bo0 + 64 * 512);                    \
        }                                                                    \
    } while (0)

#define QKV_WRITET(d) do {                                                   \
        short* base_ = LB + (d) * 20480;                                     \
        *(short8*)&base_[sr * 40 + sch]                 = ra0;               \
        *(short8*)&base_[(sr + 64) * 40 + sch]          = ra1;               \
        *(short8*)&base_[10240 + sr * 40 + sch]         = rb0;               \
        *(short8*)&base_[10240 + (sr + 64) * 40 + sch]  = rb1;               \
        if (split) {                                                         \
            *(short8*)&base_[5120 + sr * 40 + sch]                = rla0;    \
            *(short8*)&base_[5120 + (sr + 64) * 40 + sch]         = rla1;    \
            *(short8*)&base_[15360 + sr * 40 + sch]               = rlb0;    \
            *(short8*)&base_[15360 + (sr + 64) * 40 + sch]        = rlb1;    \
        }                                                                    \
    } while (0)

    QKV_LOADT(0);
    QKV_WRITET(0);
    __syncthreads();

#pragma unroll 2
    for (int t = 0; t < 16; t++) {
        if (t < 15) QKV_LOADT((t + 1) * 32);           // prefetch next tile
        const short* base = LB + (t & 1) * 20480;
        short8 ah[4], bh[4];
#pragma unroll
        for (int i = 0; i < 4; i++)
            ah[i] = *(const short8*)&base[(wr + i * 16 + fr) * 40 + fq];
#pragma unroll
        for (int j = 0; j < 4; j++)
            bh[j] = *(const short8*)&base[10240 + (wc + j * 16 + fr) * 40 + fq];
        if (split) {
            short8 al[4], bl[4];
#pragma unroll
            for (int i = 0; i < 4; i++)
                al[i] = *(const short8*)&base[5120 + (wr + i * 16 + fr) * 40 + fq];
#pragma unroll
            for (int j = 0; j < 4; j++)
                bl[j] = *(const short8*)&base[15360 + (wc + j * 16 + fr) * 40 + fq];
#pragma unroll
            for (int i = 0; i < 4; i++)
#pragma unroll
                for (int j = 0; j < 4; j++) {
                    acc[i][j] = __builtin_amdgcn_mfma_f32_16x16x32_bf16(ah[i], bh[j], acc[i][j], 0, 0, 0);
                    acc[i][j] = __builtin_amdgcn_mfma_f32_16x16x32_bf16(ah[i], bl[j], acc[i][j], 0, 0, 0);
                    acc[i][j] = __builtin_amdgcn_mfma_f32_16x16x32_bf16(al[i], bh[j], acc[i][j], 0, 0, 0);
                }
        } else {
#pragma unroll
            for (int i = 0; i < 4; i++)
#pragma unroll
                for (int j = 0; j < 4; j++)
                    acc[i][j] = __builtin_amdgcn_mfma_f32_16x16x32_bf16(ah[i], bh[j], acc[i][j], 0, 0, 0);
        }
        if (t < 15) QKV_WRITET((t + 1) & 1);           // fill other buffer
        __syncthreads();
    }

    const int cr = (lane >> 4) * 4, cc = lane & 15;
    if (seg == 2) {
        // LDS transpose: S2[c_local][k'_local], rows padded to 136 shorts
        short (*S2)[136] = (short(*)[136])LB;
#pragma unroll
        for (int i = 0; i < 4; i++)
#pragma unroll
            for (int j = 0; j < 4; j++)
#pragma unroll
                for (int r = 0; r < 4; r++)
                    S2[wc + j * 16 + cc][wr + i * 16 + cr + r] =
                        (short)f2bf(acc[i][j][r]);
        __syncthreads();
        const int orow = tid >> 1;            // c_local 0..127
        const int os   = (tid & 1) * 64;      // k'_local chunk
        unsigned short* dst = vt + (long)(arow0 >> 8) * 131072
                            + (long)(j0 + orow) * 256 + (arow0 & 255) + os;
#pragma unroll
        for (int c8 = 0; c8 < 8; c8++)
            *(short8*)(dst + c8 * 8) = *(const short8*)&S2[orow][os + c8 * 8];
    } else {
#pragma unroll
        for (int i = 0; i < 4; i++)
#pragma unroll
            for (int j = 0; j < 4; j++) {
                const int gj = j0 + wc + j * 16 + cc;
#pragma unroll
                for (int r = 0; r < 4; r++) {
                    const int gi = arow0 + wr + i * 16 + cr + r;
                    const float v = acc[i][j][r];
                    const unsigned short h = f2bf(v);
                    const unsigned short lo = f2bf(v - bf2f(h));
                    if (seg == 0) {
                        const long orow = (long)((gi & 7) * 1024 + ((gi >> 3) & 15) * 64 + (gi >> 7));
                        qh[orow * 512 + gj] = h;
                        ql[orow * 512 + gj] = lo;
                    } else {
                        kh[(long)gi * 512 + gj] = h;
                        kl[(long)gi * 512 + gj] = lo;
                    }
                }
            }
    }
#undef QKV_LOADT
#undef QKV_WRITET
}

// ---------------------------------------------------------------------------
// sim GEMM, 64x64 tiles (512 blocks), bf16x3 on split pairs, epilogue scale
// rs_k[i]*rs_q[j].
// ---------------------------------------------------------------------------
__global__ __launch_bounds__(256) void gemm_sim64(
    const short* __restrict__ Ah, const short* __restrict__ Al,
    const short* __restrict__ Bh, const short* __restrict__ Bl,
    float* __restrict__ Out, const float* __restrict__ rs)
{
    const int z = blockIdx.z;
    Ah += (long)z * 131072;  Al += (long)z * 131072;
    Bh += (long)z * 524288;  Bl += (long)z * 524288;
    Out += (long)z * 262144;
    const float* rsq = rs + (long)z * 1024;
    const float* rsk = rs + 8192 + (long)z * 256;

    __shared__ __align__(16) short Ash[64][40];
    __shared__ __align__(16) short Asl[64][40];
    __shared__ __align__(16) short Bsh[64][40];
    __shared__ __align__(16) short Bsl[64][40];

    const int tid  = threadIdx.x;
    const int lane = tid & 63, wv = tid >> 6;
    const int wr = (wv >> 1) * 32, wc = (wv & 1) * 32;
    const int i0 = blockIdx.x * 64, j0 = blockIdx.y * 64;

    floatx4 acc[2][2];
#pragma unroll
    for (int i = 0; i < 2; i++)
#pragma unroll
        for (int j = 0; j < 2; j++) acc[i][j] = {0.f, 0.f, 0.f, 0.f};

    const int sr = tid >> 2, sch = (tid & 3) * 8;
    const int fr = lane & 15, fq = (lane >> 4) * 8;

    for (int k0 = 0; k0 < 512; k0 += 32) {
        const long ao = (long)(i0 + sr) * 512 + k0 + sch;
        const long bo = (long)(j0 + sr) * 512 + k0 + sch;
        *(short8*)&Ash[sr][sch] = *(const short8*)(Ah + ao);
        *(short8*)&Asl[sr][sch] = *(const short8*)(Al + ao);
        *(short8*)&Bsh[sr][sch] = *(const short8*)(Bh + bo);
        *(short8*)&Bsl[sr][sch] = *(const short8*)(Bl + bo);
        __syncthreads();
        short8 ah[2], al[2], bh[2], bl[2];
#pragma unroll
        for (int i = 0; i < 2; i++) {
            ah[i] = *(const short8*)&Ash[wr + i * 16 + fr][fq];
            al[i] = *(const short8*)&Asl[wr + i * 16 + fr][fq];
        }
#pragma unroll
        for (int j = 0; j < 2; j++) {
            bh[j] = *(const short8*)&Bsh[wc + j * 16 + fr][fq];
            bl[j] = *(const short8*)&Bsl[wc + j * 16 + fr][fq];
        }
#pragma unroll
        for (int i = 0; i < 2; i++)
#pragma unroll
            for (int j = 0; j < 2; j++) {
                acc[i][j] = __builtin_amdgcn_mfma_f32_16x16x32_bf16(ah[i], bh[j], acc[i][j], 0, 0, 0);
                acc[i][j] = __builtin_amdgcn_mfma_f32_16x16x32_bf16(ah[i], bl[j], acc[i][j], 0, 0, 0);
                acc[i][j] = __builtin_amdgcn_mfma_f32_16x16x32_bf16(al[i], bh[j], acc[i][j], 0, 0, 0);
            }
        __syncthreads();
    }

    const int cr = (lane >> 4) * 4, cc = lane & 15;
#pragma unroll
    for (int i = 0; i < 2; i++)
#pragma unroll
        for (int j = 0; j < 2; j++) {
            const int gj = j0 + wc + j * 16 + cc;
            const float sq = rsq[gj];
#pragma unroll
            for (int r = 0; r < 4; r++) {
                const int gi = i0 + wr + i * 16 + cr + r;
                Out[(long)gi * 1024 + gj] = acc[i][j][r] * rsk[gi] * sq;
            }
        }
}

// ---------------------------------------------------------------------------
// Plain bf16 MFMA GEMM (T@V and final proj), 128x128, BK=32, pure bf16.
// ---------------------------------------------------------------------------
template <bool BIAS, bool OPERM, bool OUT_BF16>
__global__ __launch_bounds__(256) void gemm_bf16(
    const short* __restrict__ A, const short* __restrict__ B,
    const float* __restrict__ bias, void* __restrict__ OutV,
    int Kdim, int lda, int ldb, int ldo, long sA, long sB, long sO)
{
    __shared__ __align__(16) short As[128][40];
    __shared__ __align__(16) short Bs[128][40];

    const int tid  = threadIdx.x;
    const int lane = tid & 63, wv = tid >> 6;
    const int wr = (wv >> 1) * 64, wc = (wv & 1) * 64;
    const int i0 = blockIdx.x * 128, j0 = blockIdx.y * 128;

    floatx4 acc[4][4];
#pragma unroll
    for (int i = 0; i < 4; i++)
#pragma unroll
        for (int j = 0; j < 4; j++) acc[i][j] = {0.f, 0.f, 0.f, 0.f};

    const int sr = tid >> 2, sk = (tid & 3) * 8;
    const int fr = lane & 15, fq = (lane >> 4) * 8;
    const short* pa = A + (long)blockIdx.z * sA;
    const short* pb = B + (long)blockIdx.z * sB;

    for (int k0 = 0; k0 < Kdim; k0 += 32) {
#pragma unroll
        for (int p = 0; p < 2; p++) {
            *(short8*)&As[sr + p * 64][sk] =
                *(const short8*)(pa + (long)(i0 + sr + p * 64) * lda + k0 + sk);
            *(short8*)&Bs[sr + p * 64][sk] =
                *(const short8*)(pb + (long)(j0 + sr + p * 64) * ldb + k0 + sk);
        }
        __syncthreads();
        short8 af[4], bf[4];
#pragma unroll
        for (int i = 0; i < 4; i++) af[i] = *(const short8*)&As[wr + i * 16 + fr][fq];
#pragma unroll
        for (int j = 0; j < 4; j++) bf[j] = *(const short8*)&Bs[wc + j * 16 + fr][fq];
#pragma unroll
        for (int i = 0; i < 4; i++)
#pragma unroll
            for (int j = 0; j < 4; j++)
                acc[i][j] = __builtin_amdgcn_mfma_f32_16x16x32_bf16(af[i], bf[j], acc[i][j], 0, 0, 0);
        __syncthreads();
    }

    float* Of = nullptr; unsigned short* Ob = nullptr;
    if constexpr (OUT_BF16) Ob = (unsigned short*)OutV + (long)blockIdx.z * sO;
    else                    Of = (float*)OutV + (long)blockIdx.z * sO;
    const int cr = (lane >> 4) * 4, cc = lane & 15;
#pragma unroll
    for (int i = 0; i < 4; i++) {
#pragma unroll
        for (int j = 0; j < 4; j++) {
            const int gj = j0 + wc + j * 16 + cc;
            float bb = 0.0f;
            if constexpr (BIAS) bb = bias[gj];
#pragma unroll
            for (int r = 0; r < 4; r++) {
                const int gi = i0 + wr + i * 16 + cr + r;
                float v = acc[i][j][r] + bb;
                long idx;
                if constexpr (OPERM)
                    idx = (long)((gi & 63) * 128 + ((gi >> 6) & 15) * 8 + (gi >> 10)) * ldo + gj;
                else
                    idx = (long)gi * ldo + gj;
                if constexpr (OUT_BF16) Ob[idx] = f2bf(v);
                else                    Of[idx] = v;
            }
        }
    }
}

// ---------------------------------------------------------------------------
// Row reciprocal-norms from split pairs: rows 0..8191 q, 8192..10239 k.
// ---------------------------------------------------------------------------
__global__ __launch_bounds__(256) void rownorm(
    const unsigned short* __restrict__ qh, const unsigned short* __restrict__ ql,
    const unsigned short* __restrict__ kh, const unsigned short* __restrict__ kl,
    float* __restrict__ rs)
{
    const int row  = blockIdx.x * 4 + (threadIdx.x >> 6);
    const int lane = threadIdx.x & 63;
    const unsigned short *ph, *pl;
    long r;
    if (row < 8192) { ph = qh; pl = ql; r = row; }
    else            { ph = kh; pl = kl; r = row - 8192; }
    const long o = r * 512 + lane * 8;
    ushort4 h0 = *(const ushort4*)(ph + o), h1 = *(const ushort4*)(ph + o + 4);
    ushort4 l0 = *(const ushort4*)(pl + o), l1 = *(const ushort4*)(pl + o + 4);
    float ss = 0.0f;
    const unsigned short hv[8] = {h0.x, h0.y, h0.z, h0.w, h1.x, h1.y, h1.z, h1.w};
    const unsigned short lv[8] = {l0.x, l0.y, l0.z, l0.w, l1.x, l1.y, l1.z, l1.w};
#pragma unroll
    for (int i = 0; i < 8; i++) {
        const float v = bf2f(hv[i]) + bf2f(lv[i]);
        ss = fmaf(v, v, ss);
    }
#pragma unroll
    for (int off = 32; off; off >>= 1) ss += __shfl_xor(ss, off, 64);
    if (lane == 0) rs[row] = 1.0f / fmaxf(sqrtf(ss), 1e-12f);
}

// ---------------------------------------------------------------------------
// Sinkhorn, rotated dual layouts + DPP + permlane butterflies + early exit.
// ---------------------------------------------------------------------------
__global__ __launch_bounds__(256, 2) void sinkhorn5(
    const float* __restrict__ sim, float* __restrict__ score,
    unsigned short* __restrict__ Tt)
{
    const int lane = threadIdx.x & 63;
    const int bk   = blockIdx.x * 4 + (threadIdx.x >> 6);
    const float* S = sim + (long)bk * 1024;
    const int m = lane & 15, g = lane >> 4;

    int idx[16];
    idx[0] = m;
    idx[1]  = RRI(m, 0x121); idx[2]  = RRI(m, 0x122); idx[3]  = RRI(m, 0x123);
    idx[4]  = RRI(m, 0x124); idx[5]  = RRI(m, 0x125); idx[6]  = RRI(m, 0x126);
    idx[7]  = RRI(m, 0x127); idx[8]  = RRI(m, 0x128); idx[9]  = RRI(m, 0x129);
    idx[10] = RRI(m, 0x12a); idx[11] = RRI(m, 0x12b); idx[12] = RRI(m, 0x12c);
    idx[13] = RRI(m, 0x12d); idx[14] = RRI(m, 0x12e); idx[15] = RRI(m, 0x12f);

    float K1[16], K2R[16], sv[16];
#pragma unroll
    for (int j = 0; j < 16; j++) {
        K1[j] = __expf((S[m * 64 + g * 16 + idx[j]] - 1.0f) * 20.0f);
        const float s_ = S[idx[j] * 64 + lane];
        sv[j]  = s_;
        K2R[j] = __expf((s_ - 1.0f) * 20.0f);
    }

    const float muP = 0.0625f + 1e-8f;
    const float nuP = 0.015625f + 1e-8f;
    float b = 1.0f;
    float aB[16], bB[16];
#pragma unroll
    for (int j = 0; j < 16; j++) bB[j] = 1.0f;

#pragma unroll 1
    for (int it = 0; it < 100; it++) {
        float s0 = 0, s1 = 0, s2 = 0, s3 = 0;
#pragma unroll
        for (int j = 0; j < 4; j++) {
            s0 = fmaf(K1[j],      bB[j],      s0);
            s1 = fmaf(K1[4 + j],  bB[4 + j],  s1);
            s2 = fmaf(K1[8 + j],  bB[8 + j],  s2);
            s3 = fmaf(K1[12 + j], bB[12 + j], s3);
        }
        float s = (s0 + s1) + (s2 + s3);
        s = xadd16(s);
        s = xadd32(s);
        const float a = muP * fastrcp(s);
        GATH16(aB, a);
        float t0 = 0, t1 = 0, t2 = 0, t3 = 0;
#pragma unroll
        for (int j = 0; j < 4; j++) {
            t0 = fmaf(K2R[j],      aB[j],      t0);
            t1 = fmaf(K2R[4 + j],  aB[4 + j],  t1);
            t2 = fmaf(K2R[8 + j],  aB[8 + j],  t2);
            t3 = fmaf(K2R[12 + j], aB[12 + j], t3);
        }
        const float bp_ = b;
        b = nuP * fastrcp((t0 + t1) + (t2 + t3));
        GATH16(bB, b);
        const int conv = __builtin_fabsf(b - bp_) <= 1e-5f * __builtin_fabsf(b);
        if (__all(conv)) break;
    }

    float* Sc = score + (long)bk * 1024;
    unsigned short* Tp = Tt + (long)(bk >> 8) * 262144 + (bk & 255);
#pragma unroll
    for (int j = 0; j < 16; j++) {
        const int row = idx[j];
        const float Tv = aB[j] * K2R[j] * b;
        Sc[row * 64 + lane] = 1024.0f * sv[j] * Tv;
        Tp[(long)(row * 64 + lane) * 256] = f2bf(Tv);
    }
}

extern "C" void kernel_launch(void* const* d_in, const int* in_sizes, int n_in,
                              void* d_out, int out_size, void* d_ws, size_t ws_size,
                              hipStream_t stream)
{
    (void)in_sizes; (void)n_in; (void)out_size; (void)ws_size;
    const float* xq = (const float*)d_in[0];
    const float* xk = (const float*)d_in[1];
    const float* xv = (const float*)d_in[2];
    const float* Wq = (const float*)d_in[3];
    const float* Wk = (const float*)d_in[4];
    const float* Wv = (const float*)d_in[5];
    const float* Wp = (const float*)d_in[6];
    const float* bp = (const float*)d_in[7];

    float* out_x     = (float*)d_out;           // (Nq,M,B,C) = 8192 x 512
    float* out_score = out_x + 8192L * 512;     // (B,K,M,Nq) = 2048 x 1024

    // workspace (47.1 MB of the proven 48 MB); regions reused across phases
    char* W = (char*)d_ws;
    const long MB = 1 << 20;
    unsigned short* qh   = (unsigned short*)(W + 0);        // 8MB [b][mn][c]
    unsigned short* ql   = (unsigned short*)(W + 8 * MB);   // 8MB
    unsigned short* xq_h = (unsigned short*)(W + 16 * MB);  // 8MB, dead after qkv
    float*          simb = (float*)(W + 16 * MB);           // 8MB (reuse)
    unsigned short* xq_l = (unsigned short*)(W + 24 * MB);  // 8MB, dead after qkv
    unsigned short* xpre = (unsigned short*)(W + 24 * MB);  // 8MB (reuse)
    unsigned short* xk_h = (unsigned short*)(W + 32 * MB);  // 2MB, dead after qkv
    unsigned short* xk_l = (unsigned short*)(W + 34 * MB);  // 2MB
    unsigned short* Tt   = (unsigned short*)(W + 32 * MB);  // 4MB (reuse)
    unsigned short* xv_b = (unsigned short*)(W + 36 * MB);  // 2MB
    unsigned short* kh   = (unsigned short*)(W + 38 * MB);  // 2MB [b][k'][c]
    unsigned short* kl   = (unsigned short*)(W + 40 * MB);  // 2MB
    unsigned short* vt   = (unsigned short*)(W + 42 * MB);  // 2MB [b][c][k']
    unsigned short* wqh  = (unsigned short*)(W + 44 * MB);
    unsigned short* wql  = (unsigned short*)(W + 44 * MB + 1 * 524288);
    unsigned short* wkh  = (unsigned short*)(W + 44 * MB + 2 * 524288);
    unsigned short* wkl  = (unsigned short*)(W + 44 * MB + 3 * 524288);
    unsigned short* wvb  = (unsigned short*)(W + 44 * MB + 4 * 524288);
    unsigned short* wpb  = (unsigned short*)(W + 44 * MB + 5 * 524288);
    float*          rs   = (float*)(W + 47 * MB);           // 40KB

    const dim3 blk(256);

    // 1: precast/split all fp32 operands (memory-bound, one dispatch)
    prep<<<7168, blk, 0, stream>>>(xq, xk, xv, Wq, Wk, Wv, Wp,
                                   xq_h, xq_l, xk_h, xk_l, xv_b,
                                   wqh, wql, wkh, wkl, wvb, wpb);

    // 2: fused q/k/v projections on bf16 operands (128x128, double-buffered)
    gemm_qkv2<<<dim3(96, 4), blk, 0, stream>>>(
        xq_h, xq_l, xk_h, xk_l, xv_b, wqh, wql, wkh, wkl, wvb,
        qh, ql, kh, kl, vt);

    // 3: reciprocal row norms
    rownorm<<<2560, blk, 0, stream>>>(qh, ql, kh, kl, rs);

    // 4: sim[b][k'][mn] = (k.q) * rs_k * rs_q
    gemm_sim64<<<dim3(4, 16, 8), blk, 0, stream>>>(
        (const short*)kh, (const short*)kl, (const short*)qh, (const short*)ql,
        simb, rs);

    // 5: Sinkhorn -> score (out) + T bf16 [b][mn][k']
    sinkhorn5<<<512, blk, 0, stream>>>(simb, out_score, Tt);

    // 6: xpre[b][mn][c] = sum_k' T[b][mn][k'] * v[b][k'][c]
    gemm_bf16<false, false, true><<<dim3(8, 4, 8), blk, 0, stream>>>(
        (const short*)Tt, (const short*)vt, nullptr, xpre,
        256, 256, 256, 512, 262144, 131072, 524288);

    // 7: x = xpre @ Wp^T + bp, rows (b,mn)->(n,m,b), fp32 out
    gemm_bf16<true, true, false><<<dim3(64, 4), blk, 0, stream>>>(
        (const short*)xpre, (const short*)wpb, bp, out_x,
        512, 512, 512, 512, 0, 0, 0);
}

// Round 4
// 193.444 us; speedup vs baseline: 1.0345x; 1.0148x over previous
//
#include <hip/hip_runtime.h>

// ---------------------------------------------------------------------------
// AttentionOT  (Nq=64, M=16, B=8, K=256, C=512)
//   Front (error-critical, feeds exp(20*sim)): bf16x3 split MFMA (Markidis),
//     operands PRE-SPLIT by a memory-bound prep pass.
//   Back half: plain bf16 MFMA, weights precast.
//   Sinkhorn (round 6): launch_bounds(256,2), permlane16/32 butterflies,
//     fixed-point early exit.  (verified: 49us -> out of top-5)
//   qkv GEMM (round 9): round-8's reg-staged double-buffer gave ~0 (compiler
//     already pipelines; barrier drain structural — m99/m100 reproduced).
//     Now m97-structure: global_load_lds width=16 direct HBM->LDS staging
//     (m151: +35% vs reg-staging at this exact 128x128/BK=32 geometry),
//     single 32KB linear LDS buffer (unpadded, required by global_load_lds),
//     2 barriers per K-step. Staging VALU/VGPR eliminated.
//   7 dispatches: prep -> qkv -> rownorm -> sim -> sinkhorn -> T@V -> proj.
// ---------------------------------------------------------------------------

typedef short   short8  __attribute__((ext_vector_type(8)));
typedef float   floatx4 __attribute__((ext_vector_type(4)));
typedef unsigned int uint2e __attribute__((ext_vector_type(2)));

static __device__ __forceinline__ float fastrcp(float x) {
    return __builtin_amdgcn_rcpf(x);
}
static __device__ __forceinline__ unsigned short f2bf(float f) {
    union { float f; unsigned u; } c; c.f = f;
    unsigned r = c.u + 0x7FFF + ((c.u >> 16) & 1);   // RNE
    return (unsigned short)(r >> 16);
}
static __device__ __forceinline__ float bf2f(unsigned short h) {
    union { unsigned u; float f; } c; c.u = (unsigned)h << 16;
    return c.f;
}

// HBM -> LDS direct DMA, 16B per lane. LDS dest must be wave-uniform base;
// HW writes lane i at base + i*16 (m03/m97/m104).
static __device__ __forceinline__ void gll16(const unsigned short* g, short* l) {
    __builtin_amdgcn_global_load_lds(
        (const __attribute__((address_space(1))) void*)g,
        (__attribute__((address_space(3))) void*)l, 16, 0, 0);
}

// Cross-lane butterfly adds via gfx950 permlane16/32_swap (full-rate VALU,
// vs ~120cyc ds_bpermute for shfl_xor). With both operands equal, x+y equals
// s + shfl_xor(s, 16) (resp. 32) on every lane.
#if __has_builtin(__builtin_amdgcn_permlane16_swap)
static __device__ __forceinline__ float xadd16(float s) {
    uint2e r = __builtin_amdgcn_permlane16_swap(
        __float_as_uint(s), __float_as_uint(s), false, false);
    return __uint_as_float(r.x) + __uint_as_float(r.y);
}
#else
static __device__ __forceinline__ float xadd16(float s) {
    return s + __shfl_xor(s, 16, 64);
}
#endif
#if __has_builtin(__builtin_amdgcn_permlane32_swap)
static __device__ __forceinline__ float xadd32(float s) {
    uint2e r = __builtin_amdgcn_permlane32_swap(
        __float_as_uint(s), __float_as_uint(s), false, false);
    return __uint_as_float(r.x) + __uint_as_float(r.y);
}
#else
static __device__ __forceinline__ float xadd32(float s) {
    return s + __shfl_xor(s, 32, 64);
}
#endif

#define RRI(x, C) __builtin_amdgcn_update_dpp(0, (x), (C), 0xf, 0xf, true)
#define RRF(x, C) __int_as_float(RRI(__float_as_int(x), (C)))
#define GATH16(d, s) do { d[0] = (s);                                        \
    d[1]  = RRF((s), 0x121); d[2]  = RRF((s), 0x122);                        \
    d[3]  = RRF((s), 0x123); d[4]  = RRF((s), 0x124);                        \
    d[5]  = RRF((s), 0x125); d[6]  = RRF((s), 0x126);                        \
    d[7]  = RRF((s), 0x127); d[8]  = RRF((s), 0x128);                        \
    d[9]  = RRF((s), 0x129); d[10] = RRF((s), 0x12a);                        \
    d[11] = RRF((s), 0x12b); d[12] = RRF((s), 0x12c);                        \
    d[13] = RRF((s), 0x12d); d[14] = RRF((s), 0x12e);                        \
    d[15] = RRF((s), 0x12f); } while (0)

// ---------------------------------------------------------------------------
// prep: fp32 -> bf16 split (xq,xk,Wq,Wk) / cast (xv,Wv,Wp).  One dispatch,
// one float4 per thread, memory-bound.
// ---------------------------------------------------------------------------
__global__ __launch_bounds__(256) void prep(
    const float* __restrict__ xq, const float* __restrict__ xk,
    const float* __restrict__ xv, const float* __restrict__ Wq,
    const float* __restrict__ Wk, const float* __restrict__ Wv,
    const float* __restrict__ Wp,
    unsigned short* __restrict__ xqh, unsigned short* __restrict__ xql,
    unsigned short* __restrict__ xkh, unsigned short* __restrict__ xkl,
    unsigned short* __restrict__ xvb,
    unsigned short* __restrict__ wqh, unsigned short* __restrict__ wql,
    unsigned short* __restrict__ wkh, unsigned short* __restrict__ wkl,
    unsigned short* __restrict__ wvb, unsigned short* __restrict__ wpb)
{
    const int b = blockIdx.x;
    const float* src; unsigned short *dh, *dl; long base;
    if (b < 4096)      { src = xq; dh = xqh; dl = xql;     base = (long)b * 256; }
    else if (b < 5120) { src = xk; dh = xkh; dl = xkl;     base = (long)(b - 4096) * 256; }
    else if (b < 6144) { src = xv; dh = xvb; dl = nullptr; base = (long)(b - 5120) * 256; }
    else if (b < 6400) { src = Wq; dh = wqh; dl = wql;     base = (long)(b - 6144) * 256; }
    else if (b < 6656) { src = Wk; dh = wkh; dl = wkl;     base = (long)(b - 6400) * 256; }
    else if (b < 6912) { src = Wv; dh = wvb; dl = nullptr; base = (long)(b - 6656) * 256; }
    else               { src = Wp; dh = wpb; dl = nullptr; base = (long)(b - 6912) * 256; }
    const long i = base + threadIdx.x;
    float4 v = ((const float4*)src)[i];
    ushort4 h;
    h.x = f2bf(v.x); h.y = f2bf(v.y); h.z = f2bf(v.z); h.w = f2bf(v.w);
    ((ushort4*)dh)[i] = h;
    if (dl) {
        ushort4 l;
        l.x = f2bf(v.x - bf2f(h.x)); l.y = f2bf(v.y - bf2f(h.y));
        l.z = f2bf(v.z - bf2f(h.z)); l.w = f2bf(v.w - bf2f(h.w));
        ((ushort4*)dl)[i] = l;
    }
}

// ---------------------------------------------------------------------------
// Fused q/k/v projection on PRECONVERTED bf16 operands.  blockIdx.x:
// 0..63 q (split3), 64..79 k (split3), 80..95 v (plain).  128x128, BK=32.
// Round 9 (m97 structure): global_load_lds width-16 staging into a single
// 32KB linear LDS buffer (Ah@0, Al@4096, Bh@8192, Bl@12288 shorts, rows of
// 32 shorts, NO padding), 2 barriers per K-step. Per wave per K-step:
// 8 gl_lds (split) / 4 (v), each 1KB (16 rows x 64B).
// Epilogues: q -> qh/ql permuted rows; k -> kh/kl; v -> vt[b][c][k'] via
// LDS transpose (coalesced 16B stores).
// ---------------------------------------------------------------------------
__global__ __launch_bounds__(256, 2) void gemm_qkv2(
    const unsigned short* __restrict__ xqh, const unsigned short* __restrict__ xql,
    const unsigned short* __restrict__ xkh, const unsigned short* __restrict__ xkl,
    const unsigned short* __restrict__ xvb,
    const unsigned short* __restrict__ wqh, const unsigned short* __restrict__ wql,
    const unsigned short* __restrict__ wkh, const unsigned short* __restrict__ wkl,
    const unsigned short* __restrict__ wvb,
    unsigned short* __restrict__ qh, unsigned short* __restrict__ ql,
    unsigned short* __restrict__ kh, unsigned short* __restrict__ kl,
    unsigned short* __restrict__ vt)
{
    // 17408 shorts = 34 KB. Staging uses first 16384 (4 x [128][32] linear);
    // v-epilogue reuses as S2[128][136].
    __shared__ __align__(16) short LB[17408];

    const int bx = blockIdx.x;
    const unsigned short *Ah, *Al, *Bh, *Bl;
    int seg, arow0;
    if (bx < 64)      { Ah = xqh; Al = xql; Bh = wqh; Bl = wql; arow0 = bx * 128;        seg = 0; }
    else if (bx < 80) { Ah = xkh; Al = xkl; Bh = wkh; Bl = wkl; arow0 = (bx - 64) * 128; seg = 1; }
    else              { Ah = xvb; Al = xvb; Bh = wvb; Bl = wvb; arow0 = (bx - 80) * 128; seg = 2; }
    const bool split = (seg != 2);

    const int tid  = threadIdx.x;
    const int lane = tid & 63, wv = tid >> 6;
    const int wr = (wv >> 1) * 64, wc = (wv & 1) * 64;
    const int j0 = blockIdx.y * 128;

    floatx4 acc[4][4];
#pragma unroll
    for (int i = 0; i < 4; i++)
#pragma unroll
        for (int j = 0; j < 4; j++) acc[i][j] = {0.f, 0.f, 0.f, 0.f};

    // staging geometry: wave wv owns rows [32wv, 32wv+32) of each array;
    // per gl_lds instr, lane l covers row +l>>2, bytes (l&3)*16.
    const int lrow = lane >> 2;
    const int lch  = (lane & 3) * 8;       // element offset within row
    const int grow = 32 * wv;              // wave-uniform row base
    const long gA0 = (long)(arow0 + grow + lrow) * 512 + lch;
    const long gB0 = (long)(j0    + grow + lrow) * 512 + lch;
    short* const lA0 = LB + grow * 32;             // wave-uniform LDS bases
    short* const lA1 = LB + (grow + 16) * 32;
    short* const lB0 = LB + 8192 + grow * 32;
    short* const lB1 = LB + 8192 + (grow + 16) * 32;
    short* const lAl0 = LB + 4096 + grow * 32;
    short* const lAl1 = LB + 4096 + (grow + 16) * 32;
    short* const lBl0 = LB + 12288 + grow * 32;
    short* const lBl1 = LB + 12288 + (grow + 16) * 32;

    const int fr = lane & 15, fq = (lane >> 4) * 8;

    for (int k0 = 0; k0 < 512; k0 += 32) {
        gll16(Ah + gA0 + k0, lA0);
        gll16(Ah + gA0 + k0 + 16 * 512, lA1);
        gll16(Bh + gB0 + k0, lB0);
        gll16(Bh + gB0 + k0 + 16 * 512, lB1);
        if (split) {
            gll16(Al + gA0 + k0, lAl0);
            gll16(Al + gA0 + k0 + 16 * 512, lAl1);
            gll16(Bl + gB0 + k0, lBl0);
            gll16(Bl + gB0 + k0 + 16 * 512, lBl1);
        }
        __syncthreads();                    // drains vmcnt: LDS tile ready
        short8 ah[4], bh[4];
#pragma unroll
        for (int i = 0; i < 4; i++)
            ah[i] = *(const short8*)&LB[(wr + i * 16 + fr) * 32 + fq];
#pragma unroll
        for (int j = 0; j < 4; j++)
            bh[j] = *(const short8*)&LB[8192 + (wc + j * 16 + fr) * 32 + fq];
        if (split) {
            short8 al[4], bl[4];
#pragma unroll
            for (int i = 0; i < 4; i++)
                al[i] = *(const short8*)&LB[4096 + (wr + i * 16 + fr) * 32 + fq];
#pragma unroll
            for (int j = 0; j < 4; j++)
                bl[j] = *(const short8*)&LB[12288 + (wc + j * 16 + fr) * 32 + fq];
#pragma unroll
            for (int i = 0; i < 4; i++)
#pragma unroll
                for (int j = 0; j < 4; j++) {
                    acc[i][j] = __builtin_amdgcn_mfma_f32_16x16x32_bf16(ah[i], bh[j], acc[i][j], 0, 0, 0);
                    acc[i][j] = __builtin_amdgcn_mfma_f32_16x16x32_bf16(ah[i], bl[j], acc[i][j], 0, 0, 0);
                    acc[i][j] = __builtin_amdgcn_mfma_f32_16x16x32_bf16(al[i], bh[j], acc[i][j], 0, 0, 0);
                }
        } else {
#pragma unroll
            for (int i = 0; i < 4; i++)
#pragma unroll
                for (int j = 0; j < 4; j++)
                    acc[i][j] = __builtin_amdgcn_mfma_f32_16x16x32_bf16(ah[i], bh[j], acc[i][j], 0, 0, 0);
        }
        __syncthreads();                    // LDS reads done before next DMA
    }

    const int cr = (lane >> 4) * 4, cc = lane & 15;
    if (seg == 2) {
        // LDS transpose: S2[c_local][k'_local], rows padded to 136 shorts
        short (*S2)[136] = (short(*)[136])LB;
#pragma unroll
        for (int i = 0; i < 4; i++)
#pragma unroll
            for (int j = 0; j < 4; j++)
#pragma unroll
                for (int r = 0; r < 4; r++)
                    S2[wc + j * 16 + cc][wr + i * 16 + cr + r] =
                        (short)f2bf(acc[i][j][r]);
        __syncthreads();
        const int orow = tid >> 1;            // c_local 0..127
        const int os   = (tid & 1) * 64;      // k'_local chunk
        unsigned short* dst = vt + (long)(arow0 >> 8) * 131072
                            + (long)(j0 + orow) * 256 + (arow0 & 255) + os;
#pragma unroll
        for (int c8 = 0; c8 < 8; c8++)
            *(short8*)(dst + c8 * 8) = *(const short8*)&S2[orow][os + c8 * 8];
    } else {
#pragma unroll
        for (int i = 0; i < 4; i++)
#pragma unroll
            for (int j = 0; j < 4; j++) {
                const int gj = j0 + wc + j * 16 + cc;
#pragma unroll
                for (int r = 0; r < 4; r++) {
                    const int gi = arow0 + wr + i * 16 + cr + r;
                    const float v = acc[i][j][r];
                    const unsigned short h = f2bf(v);
                    const unsigned short lo = f2bf(v - bf2f(h));
                    if (seg == 0) {
                        const long orow = (long)((gi & 7) * 1024 + ((gi >> 3) & 15) * 64 + (gi >> 7));
                        qh[orow * 512 + gj] = h;
                        ql[orow * 512 + gj] = lo;
                    } else {
                        kh[(long)gi * 512 + gj] = h;
                        kl[(long)gi * 512 + gj] = lo;
                    }
                }
            }
    }
}

// ---------------------------------------------------------------------------
// sim GEMM, 64x64 tiles (512 blocks), bf16x3 on split pairs, epilogue scale
// rs_k[i]*rs_q[j].
// ---------------------------------------------------------------------------
__global__ __launch_bounds__(256) void gemm_sim64(
    const short* __restrict__ Ah, const short* __restrict__ Al,
    const short* __restrict__ Bh, const short* __restrict__ Bl,
    float* __restrict__ Out, const float* __restrict__ rs)
{
    const int z = blockIdx.z;
    Ah += (long)z * 131072;  Al += (long)z * 131072;
    Bh += (long)z * 524288;  Bl += (long)z * 524288;
    Out += (long)z * 262144;
    const float* rsq = rs + (long)z * 1024;
    const float* rsk = rs + 8192 + (long)z * 256;

    __shared__ __align__(16) short Ash[64][40];
    __shared__ __align__(16) short Asl[64][40];
    __shared__ __align__(16) short Bsh[64][40];
    __shared__ __align__(16) short Bsl[64][40];

    const int tid  = threadIdx.x;
    const int lane = tid & 63, wv = tid >> 6;
    const int wr = (wv >> 1) * 32, wc = (wv & 1) * 32;
    const int i0 = blockIdx.x * 64, j0 = blockIdx.y * 64;

    floatx4 acc[2][2];
#pragma unroll
    for (int i = 0; i < 2; i++)
#pragma unroll
        for (int j = 0; j < 2; j++) acc[i][j] = {0.f, 0.f, 0.f, 0.f};

    const int sr = tid >> 2, sch = (tid & 3) * 8;
    const int fr = lane & 15, fq = (lane >> 4) * 8;

    for (int k0 = 0; k0 < 512; k0 += 32) {
        const long ao = (long)(i0 + sr) * 512 + k0 + sch;
        const long bo = (long)(j0 + sr) * 512 + k0 + sch;
        *(short8*)&Ash[sr][sch] = *(const short8*)(Ah + ao);
        *(short8*)&Asl[sr][sch] = *(const short8*)(Al + ao);
        *(short8*)&Bsh[sr][sch] = *(const short8*)(Bh + bo);
        *(short8*)&Bsl[sr][sch] = *(const short8*)(Bl + bo);
        __syncthreads();
        short8 ah[2], al[2], bh[2], bl[2];
#pragma unroll
        for (int i = 0; i < 2; i++) {
            ah[i] = *(const short8*)&Ash[wr + i * 16 + fr][fq];
            al[i] = *(const short8*)&Asl[wr + i * 16 + fr][fq];
        }
#pragma unroll
        for (int j = 0; j < 2; j++) {
            bh[j] = *(const short8*)&Bsh[wc + j * 16 + fr][fq];
            bl[j] = *(const short8*)&Bsl[wc + j * 16 + fr][fq];
        }
#pragma unroll
        for (int i = 0; i < 2; i++)
#pragma unroll
            for (int j = 0; j < 2; j++) {
                acc[i][j] = __builtin_amdgcn_mfma_f32_16x16x32_bf16(ah[i], bh[j], acc[i][j], 0, 0, 0);
                acc[i][j] = __builtin_amdgcn_mfma_f32_16x16x32_bf16(ah[i], bl[j], acc[i][j], 0, 0, 0);
                acc[i][j] = __builtin_amdgcn_mfma_f32_16x16x32_bf16(al[i], bh[j], acc[i][j], 0, 0, 0);
            }
        __syncthreads();
    }

    const int cr = (lane >> 4) * 4, cc = lane & 15;
#pragma unroll
    for (int i = 0; i < 2; i++)
#pragma unroll
        for (int j = 0; j < 2; j++) {
            const int gj = j0 + wc + j * 16 + cc;
            const float sq = rsq[gj];
#pragma unroll
            for (int r = 0; r < 4; r++) {
                const int gi = i0 + wr + i * 16 + cr + r;
                Out[(long)gi * 1024 + gj] = acc[i][j][r] * rsk[gi] * sq;
            }
        }
}

// ---------------------------------------------------------------------------
// Plain bf16 MFMA GEMM (T@V and final proj), 128x128, BK=32, pure bf16.
// ---------------------------------------------------------------------------
template <bool BIAS, bool OPERM, bool OUT_BF16>
__global__ __launch_bounds__(256) void gemm_bf16(
    const short* __restrict__ A, const short* __restrict__ B,
    const float* __restrict__ bias, void* __restrict__ OutV,
    int Kdim, int lda, int ldb, int ldo, long sA, long sB, long sO)
{
    __shared__ __align__(16) short As[128][40];
    __shared__ __align__(16) short Bs[128][40];

    const int tid  = threadIdx.x;
    const int lane = tid & 63, wv = tid >> 6;
    const int wr = (wv >> 1) * 64, wc = (wv & 1) * 64;
    const int i0 = blockIdx.x * 128, j0 = blockIdx.y * 128;

    floatx4 acc[4][4];
#pragma unroll
    for (int i = 0; i < 4; i++)
#pragma unroll
        for (int j = 0; j < 4; j++) acc[i][j] = {0.f, 0.f, 0.f, 0.f};

    const int sr = tid >> 2, sk = (tid & 3) * 8;
    const int fr = lane & 15, fq = (lane >> 4) * 8;
    const short* pa = A + (long)blockIdx.z * sA;
    const short* pb = B + (long)blockIdx.z * sB;

    for (int k0 = 0; k0 < Kdim; k0 += 32) {
#pragma unroll
        for (int p = 0; p < 2; p++) {
            *(short8*)&As[sr + p * 64][sk] =
                *(const short8*)(pa + (long)(i0 + sr + p * 64) * lda + k0 + sk);
            *(short8*)&Bs[sr + p * 64][sk] =
                *(const short8*)(pb + (long)(j0 + sr + p * 64) * ldb + k0 + sk);
        }
        __syncthreads();
        short8 af[4], bf[4];
#pragma unroll
        for (int i = 0; i < 4; i++) af[i] = *(const short8*)&As[wr + i * 16 + fr][fq];
#pragma unroll
        for (int j = 0; j < 4; j++) bf[j] = *(const short8*)&Bs[wc + j * 16 + fr][fq];
#pragma unroll
        for (int i = 0; i < 4; i++)
#pragma unroll
            for (int j = 0; j < 4; j++)
                acc[i][j] = __builtin_amdgcn_mfma_f32_16x16x32_bf16(af[i], bf[j], acc[i][j], 0, 0, 0);
        __syncthreads();
    }

    float* Of = nullptr; unsigned short* Ob = nullptr;
    if constexpr (OUT_BF16) Ob = (unsigned short*)OutV + (long)blockIdx.z * sO;
    else                    Of = (float*)OutV + (long)blockIdx.z * sO;
    const int cr = (lane >> 4) * 4, cc = lane & 15;
#pragma unroll
    for (int i = 0; i < 4; i++) {
#pragma unroll
        for (int j = 0; j < 4; j++) {
            const int gj = j0 + wc + j * 16 + cc;
            float bb = 0.0f;
            if constexpr (BIAS) bb = bias[gj];
#pragma unroll
            for (int r = 0; r < 4; r++) {
                const int gi = i0 + wr + i * 16 + cr + r;
                float v = acc[i][j][r] + bb;
                long idx;
                if constexpr (OPERM)
                    idx = (long)((gi & 63) * 128 + ((gi >> 6) & 15) * 8 + (gi >> 10)) * ldo + gj;
                else
                    idx = (long)gi * ldo + gj;
                if constexpr (OUT_BF16) Ob[idx] = f2bf(v);
                else                    Of[idx] = v;
            }
        }
    }
}

// ---------------------------------------------------------------------------
// Row reciprocal-norms from split pairs: rows 0..8191 q, 8192..10239 k.
// ---------------------------------------------------------------------------
__global__ __launch_bounds__(256) void rownorm(
    const unsigned short* __restrict__ qh, const unsigned short* __restrict__ ql,
    const unsigned short* __restrict__ kh, const unsigned short* __restrict__ kl,
    float* __restrict__ rs)
{
    const int row  = blockIdx.x * 4 + (threadIdx.x >> 6);
    const int lane = threadIdx.x & 63;
    const unsigned short *ph, *pl;
    long r;
    if (row < 8192) { ph = qh; pl = ql; r = row; }
    else            { ph = kh; pl = kl; r = row - 8192; }
    const long o = r * 512 + lane * 8;
    ushort4 h0 = *(const ushort4*)(ph + o), h1 = *(const ushort4*)(ph + o + 4);
    ushort4 l0 = *(const ushort4*)(pl + o), l1 = *(const ushort4*)(pl + o + 4);
    float ss = 0.0f;
    const unsigned short hv[8] = {h0.x, h0.y, h0.z, h0.w, h1.x, h1.y, h1.z, h1.w};
    const unsigned short lv[8] = {l0.x, l0.y, l0.z, l0.w, l1.x, l1.y, l1.z, l1.w};
#pragma unroll
    for (int i = 0; i < 8; i++) {
        const float v = bf2f(hv[i]) + bf2f(lv[i]);
        ss = fmaf(v, v, ss);
    }
#pragma unroll
    for (int off = 32; off; off >>= 1) ss += __shfl_xor(ss, off, 64);
    if (lane == 0) rs[row] = 1.0f / fmaxf(sqrtf(ss), 1e-12f);
}

// ---------------------------------------------------------------------------
// Sinkhorn, rotated dual layouts + DPP + permlane butterflies + early exit.
// ---------------------------------------------------------------------------
__global__ __launch_bounds__(256, 2) void sinkhorn5(
    const float* __restrict__ sim, float* __restrict__ score,
    unsigned short* __restrict__ Tt)
{
    const int lane = threadIdx.x & 63;
    const int bk   = blockIdx.x * 4 + (threadIdx.x >> 6);
    const float* S = sim + (long)bk * 1024;
    const int m = lane & 15, g = lane >> 4;

    int idx[16];
    idx[0] = m;
    idx[1]  = RRI(m, 0x121); idx[2]  = RRI(m, 0x122); idx[3]  = RRI(m, 0x123);
    idx[4]  = RRI(m, 0x124); idx[5]  = RRI(m, 0x125); idx[6]  = RRI(m, 0x126);
    idx[7]  = RRI(m, 0x127); idx[8]  = RRI(m, 0x128); idx[9]  = RRI(m, 0x129);
    idx[10] = RRI(m, 0x12a); idx[11] = RRI(m, 0x12b); idx[12] = RRI(m, 0x12c);
    idx[13] = RRI(m, 0x12d); idx[14] = RRI(m, 0x12e); idx[15] = RRI(m, 0x12f);

    float K1[16], K2R[16], sv[16];
#pragma unroll
    for (int j = 0; j < 16; j++) {
        K1[j] = __expf((S[m * 64 + g * 16 + idx[j]] - 1.0f) * 20.0f);
        const float s_ = S[idx[j] * 64 + lane];
        sv[j]  = s_;
        K2R[j] = __expf((s_ - 1.0f) * 20.0f);
    }

    const float muP = 0.0625f + 1e-8f;
    const float nuP = 0.015625f + 1e-8f;
    float b = 1.0f;
    float aB[16], bB[16];
#pragma unroll
    for (int j = 0; j < 16; j++) bB[j] = 1.0f;

#pragma unroll 1
    for (int it = 0; it < 100; it++) {
        float s0 = 0, s1 = 0, s2 = 0, s3 = 0;
#pragma unroll
        for (int j = 0; j < 4; j++) {
            s0 = fmaf(K1[j],      bB[j],      s0);
            s1 = fmaf(K1[4 + j],  bB[4 + j],  s1);
            s2 = fmaf(K1[8 + j],  bB[8 + j],  s2);
            s3 = fmaf(K1[12 + j], bB[12 + j], s3);
        }
        float s = (s0 + s1) + (s2 + s3);
        s = xadd16(s);
        s = xadd32(s);
        const float a = muP * fastrcp(s);
        GATH16(aB, a);
        float t0 = 0, t1 = 0, t2 = 0, t3 = 0;
#pragma unroll
        for (int j = 0; j < 4; j++) {
            t0 = fmaf(K2R[j],      aB[j],      t0);
            t1 = fmaf(K2R[4 + j],  aB[4 + j],  t1);
            t2 = fmaf(K2R[8 + j],  aB[8 + j],  t2);
            t3 = fmaf(K2R[12 + j], aB[12 + j], t3);
        }
        const float bp_ = b;
        b = nuP * fastrcp((t0 + t1) + (t2 + t3));
        GATH16(bB, b);
        const int conv = __builtin_fabsf(b - bp_) <= 1e-5f * __builtin_fabsf(b);
        if (__all(conv)) break;
    }

    float* Sc = score + (long)bk * 1024;
    unsigned short* Tp = Tt + (long)(bk >> 8) * 262144 + (bk & 255);
#pragma unroll
    for (int j = 0; j < 16; j++) {
        const int row = idx[j];
        const float Tv = aB[j] * K2R[j] * b;
        Sc[row * 64 + lane] = 1024.0f * sv[j] * Tv;
        Tp[(long)(row * 64 + lane) * 256] = f2bf(Tv);
    }
}

extern "C" void kernel_launch(void* const* d_in, const int* in_sizes, int n_in,
                              void* d_out, int out_size, void* d_ws, size_t ws_size,
                              hipStream_t stream)
{
    (void)in_sizes; (void)n_in; (void)out_size; (void)ws_size;
    const float* xq = (const float*)d_in[0];
    const float* xk = (const float*)d_in[1];
    const float* xv = (const float*)d_in[2];
    const float* Wq = (const float*)d_in[3];
    const float* Wk = (const float*)d_in[4];
    const float* Wv = (const float*)d_in[5];
    const float* Wp = (const float*)d_in[6];
    const float* bp = (const float*)d_in[7];

    float* out_x     = (float*)d_out;           // (Nq,M,B,C) = 8192 x 512
    float* out_score = out_x + 8192L * 512;     // (B,K,M,Nq) = 2048 x 1024

    // workspace (47.1 MB of the proven 48 MB); regions reused across phases
    char* W = (char*)d_ws;
    const long MB = 1 << 20;
    unsigned short* qh   = (unsigned short*)(W + 0);        // 8MB [b][mn][c]
    unsigned short* ql   = (unsigned short*)(W + 8 * MB);   // 8MB
    unsigned short* xq_h = (unsigned short*)(W + 16 * MB);  // 8MB, dead after qkv
    float*          simb = (float*)(W + 16 * MB);           // 8MB (reuse)
    unsigned short* xq_l = (unsigned short*)(W + 24 * MB);  // 8MB, dead after qkv
    unsigned short* xpre = (unsigned short*)(W + 24 * MB);  // 8MB (reuse)
    unsigned short* xk_h = (unsigned short*)(W + 32 * MB);  // 2MB, dead after qkv
    unsigned short* xk_l = (unsigned short*)(W + 34 * MB);  // 2MB
    unsigned short* Tt   = (unsigned short*)(W + 32 * MB);  // 4MB (reuse)
    unsigned short* xv_b = (unsigned short*)(W + 36 * MB);  // 2MB
    unsigned short* kh   = (unsigned short*)(W + 38 * MB);  // 2MB [b][k'][c]
    unsigned short* kl   = (unsigned short*)(W + 40 * MB);  // 2MB
    unsigned short* vt   = (unsigned short*)(W + 42 * MB);  // 2MB [b][c][k']
    unsigned short* wqh  = (unsigned short*)(W + 44 * MB);
    unsigned short* wql  = (unsigned short*)(W + 44 * MB + 1 * 524288);
    unsigned short* wkh  = (unsigned short*)(W + 44 * MB + 2 * 524288);
    unsigned short* wkl  = (unsigned short*)(W + 44 * MB + 3 * 524288);
    unsigned short* wvb  = (unsigned short*)(W + 44 * MB + 4 * 524288);
    unsigned short* wpb  = (unsigned short*)(W + 44 * MB + 5 * 524288);
    float*          rs   = (float*)(W + 47 * MB);           // 40KB

    const dim3 blk(256);

    // 1: precast/split all fp32 operands (memory-bound, one dispatch)
    prep<<<7168, blk, 0, stream>>>(xq, xk, xv, Wq, Wk, Wv, Wp,
                                   xq_h, xq_l, xk_h, xk_l, xv_b,
                                   wqh, wql, wkh, wkl, wvb, wpb);

    // 2: fused q/k/v projections on bf16 operands (128x128, global_load_lds)
    gemm_qkv2<<<dim3(96, 4), blk, 0, stream>>>(
        xq_h, xq_l, xk_h, xk_l, xv_b, wqh, wql, wkh, wkl, wvb,
        qh, ql, kh, kl, vt);

    // 3: reciprocal row norms
    rownorm<<<2560, blk, 0, stream>>>(qh, ql, kh, kl, rs);

    // 4: sim[b][k'][mn] = (k.q) * rs_k * rs_q
    gemm_sim64<<<dim3(4, 16, 8), blk, 0, stream>>>(
        (const short*)kh, (const short*)kl, (const short*)qh, (const short*)ql,
        simb, rs);

    // 5: Sinkhorn -> score (out) + T bf16 [b][mn][k']
    sinkhorn5<<<512, blk, 0, stream>>>(simb, out_score, Tt);

    // 6: xpre[b][mn][c] = sum_k' T[b][mn][k'] * v[b][k'][c]
    gemm_bf16<false, false, true><<<dim3(8, 4, 8), blk, 0, stream>>>(
        (const short*)Tt, (const short*)vt, nullptr, xpre,
        256, 256, 256, 512, 262144, 131072, 524288);

    // 7: x = xpre @ Wp^T + bp, rows (b,mn)->(n,m,b), fp32 out
    gemm_bf16<true, true, false><<<dim3(64, 4), blk, 0, stream>>>(
        (const short*)xpre, (const short*)wpb, bp, out_x,
        512, 512, 512, 512, 0, 0, 0);
}

// Round 5
// 188.794 us; speedup vs baseline: 1.0600x; 1.0246x over previous
//
#include <hip/hip_runtime.h>

// ---------------------------------------------------------------------------
// AttentionOT  (Nq=64, M=16, B=8, K=256, C=512)
//   Front (error-critical, feeds exp(20*sim)): bf16x3 split MFMA (Markidis),
//     operands PRE-SPLIT by a memory-bound prep pass.
//   Back half: plain bf16 MFMA, weights precast.
//   Sinkhorn (round 6): launch_bounds(256,2), permlane16/32 butterflies,
//     fixed-point early exit.  (verified: 49us -> out of top-5)
//   qkv GEMM (round 10): history —
//     r1  reg-staged 2-barrier:        41.0us (compiler pipelines loads)
//     r8  reg-staged dbuf 1-barrier:  ~40us   (m99/m100 reproduced: ~0)
//     r9  gll_lds single-buf:          53.7us (DMA drain BEFORE compute =
//         latency fully exposed at 1.5 blocks/CU — no inter-block overlap)
//     r10 (this): gll_lds + DOUBLE buffer, issue-early/drain-late (T3
//         2-phase recipe): stage tile t+1 -> compute tile t -> syncthreads.
//         The vmcnt(0) drain now sits AFTER ~400cy of MFMA — overlap
//         without relying on co-resident blocks. Staging VALU still zero.
//   7 dispatches: prep -> qkv -> rownorm -> sim -> sinkhorn -> T@V -> proj.
// ---------------------------------------------------------------------------

typedef short   short8  __attribute__((ext_vector_type(8)));
typedef float   floatx4 __attribute__((ext_vector_type(4)));
typedef unsigned int uint2e __attribute__((ext_vector_type(2)));

static __device__ __forceinline__ float fastrcp(float x) {
    return __builtin_amdgcn_rcpf(x);
}
static __device__ __forceinline__ unsigned short f2bf(float f) {
    union { float f; unsigned u; } c; c.f = f;
    unsigned r = c.u + 0x7FFF + ((c.u >> 16) & 1);   // RNE
    return (unsigned short)(r >> 16);
}
static __device__ __forceinline__ float bf2f(unsigned short h) {
    union { unsigned u; float f; } c; c.u = (unsigned)h << 16;
    return c.f;
}

// HBM -> LDS direct DMA, 16B per lane. LDS dest is wave-uniform base;
// HW writes lane i at base + i*16 (m03/m97/m104).
static __device__ __forceinline__ void gll16(const unsigned short* g, short* l) {
    __builtin_amdgcn_global_load_lds(
        (const __attribute__((address_space(1))) void*)g,
        (__attribute__((address_space(3))) void*)l, 16, 0, 0);
}

// Cross-lane butterfly adds via gfx950 permlane16/32_swap (full-rate VALU,
// vs ~120cyc ds_bpermute for shfl_xor).
#if __has_builtin(__builtin_amdgcn_permlane16_swap)
static __device__ __forceinline__ float xadd16(float s) {
    uint2e r = __builtin_amdgcn_permlane16_swap(
        __float_as_uint(s), __float_as_uint(s), false, false);
    return __uint_as_float(r.x) + __uint_as_float(r.y);
}
#else
static __device__ __forceinline__ float xadd16(float s) {
    return s + __shfl_xor(s, 16, 64);
}
#endif
#if __has_builtin(__builtin_amdgcn_permlane32_swap)
static __device__ __forceinline__ float xadd32(float s) {
    uint2e r = __builtin_amdgcn_permlane32_swap(
        __float_as_uint(s), __float_as_uint(s), false, false);
    return __uint_as_float(r.x) + __uint_as_float(r.y);
}
#else
static __device__ __forceinline__ float xadd32(float s) {
    return s + __shfl_xor(s, 32, 64);
}
#endif

#define RRI(x, C) __builtin_amdgcn_update_dpp(0, (x), (C), 0xf, 0xf, true)
#define RRF(x, C) __int_as_float(RRI(__float_as_int(x), (C)))
#define GATH16(d, s) do { d[0] = (s);                                        \
    d[1]  = RRF((s), 0x121); d[2]  = RRF((s), 0x122);                        \
    d[3]  = RRF((s), 0x123); d[4]  = RRF((s), 0x124);                        \
    d[5]  = RRF((s), 0x125); d[6]  = RRF((s), 0x126);                        \
    d[7]  = RRF((s), 0x127); d[8]  = RRF((s), 0x128);                        \
    d[9]  = RRF((s), 0x129); d[10] = RRF((s), 0x12a);                        \
    d[11] = RRF((s), 0x12b); d[12] = RRF((s), 0x12c);                        \
    d[13] = RRF((s), 0x12d); d[14] = RRF((s), 0x12e);                        \
    d[15] = RRF((s), 0x12f); } while (0)

// ---------------------------------------------------------------------------
// prep: fp32 -> bf16 split (xq,xk,Wq,Wk) / cast (xv,Wv,Wp).  One dispatch,
// one float4 per thread, memory-bound.
// ---------------------------------------------------------------------------
__global__ __launch_bounds__(256) void prep(
    const float* __restrict__ xq, const float* __restrict__ xk,
    const float* __restrict__ xv, const float* __restrict__ Wq,
    const float* __restrict__ Wk, const float* __restrict__ Wv,
    const float* __restrict__ Wp,
    unsigned short* __restrict__ xqh, unsigned short* __restrict__ xql,
    unsigned short* __restrict__ xkh, unsigned short* __restrict__ xkl,
    unsigned short* __restrict__ xvb,
    unsigned short* __restrict__ wqh, unsigned short* __restrict__ wql,
    unsigned short* __restrict__ wkh, unsigned short* __restrict__ wkl,
    unsigned short* __restrict__ wvb, unsigned short* __restrict__ wpb)
{
    const int b = blockIdx.x;
    const float* src; unsigned short *dh, *dl; long base;
    if (b < 4096)      { src = xq; dh = xqh; dl = xql;     base = (long)b * 256; }
    else if (b < 5120) { src = xk; dh = xkh; dl = xkl;     base = (long)(b - 4096) * 256; }
    else if (b < 6144) { src = xv; dh = xvb; dl = nullptr; base = (long)(b - 5120) * 256; }
    else if (b < 6400) { src = Wq; dh = wqh; dl = wql;     base = (long)(b - 6144) * 256; }
    else if (b < 6656) { src = Wk; dh = wkh; dl = wkl;     base = (long)(b - 6400) * 256; }
    else if (b < 6912) { src = Wv; dh = wvb; dl = nullptr; base = (long)(b - 6656) * 256; }
    else               { src = Wp; dh = wpb; dl = nullptr; base = (long)(b - 6912) * 256; }
    const long i = base + threadIdx.x;
    float4 v = ((const float4*)src)[i];
    ushort4 h;
    h.x = f2bf(v.x); h.y = f2bf(v.y); h.z = f2bf(v.z); h.w = f2bf(v.w);
    ((ushort4*)dh)[i] = h;
    if (dl) {
        ushort4 l;
        l.x = f2bf(v.x - bf2f(h.x)); l.y = f2bf(v.y - bf2f(h.y));
        l.z = f2bf(v.z - bf2f(h.z)); l.w = f2bf(v.w - bf2f(h.w));
        ((ushort4*)dl)[i] = l;
    }
}

// ---------------------------------------------------------------------------
// Fused q/k/v projection on PRECONVERTED bf16 operands.  blockIdx.x:
// 0..63 q (split3), 64..79 k (split3), 80..95 v (plain).  128x128, BK=32.
// Round 10: global_load_lds width-16 staging, LDS DOUBLE buffer (2 x 32KB,
// linear [128][32] arrays), T3 2-phase schedule: issue DMAs for tile t+1
// first, then ds_read+MFMA tile t, then ONE __syncthreads (vmcnt/lgkm drain
// lands after compute -> DMA latency overlapped).
// Epilogues: q -> qh/ql permuted rows; k -> kh/kl; v -> vt[b][c][k'] via
// LDS transpose (coalesced 16B stores).
// ---------------------------------------------------------------------------
__global__ __launch_bounds__(256, 2) void gemm_qkv2(
    const unsigned short* __restrict__ xqh, const unsigned short* __restrict__ xql,
    const unsigned short* __restrict__ xkh, const unsigned short* __restrict__ xkl,
    const unsigned short* __restrict__ xvb,
    const unsigned short* __restrict__ wqh, const unsigned short* __restrict__ wql,
    const unsigned short* __restrict__ wkh, const unsigned short* __restrict__ wkl,
    const unsigned short* __restrict__ wvb,
    unsigned short* __restrict__ qh, unsigned short* __restrict__ ql,
    unsigned short* __restrict__ kh, unsigned short* __restrict__ kl,
    unsigned short* __restrict__ vt)
{
    // 2 staging buffers of 16384 shorts (32KB) each:
    //   +0 Ah[128][32], +4096 Al, +8192 Bh, +12288 Bl  (linear, unpadded)
    // v-epilogue reuses front 17408 shorts as S2[128][136].
    __shared__ __align__(16) short LB[32768];

    const int bx = blockIdx.x;
    const unsigned short *Ah, *Al, *Bh, *Bl;
    int seg, arow0;
    if (bx < 64)      { Ah = xqh; Al = xql; Bh = wqh; Bl = wql; arow0 = bx * 128;        seg = 0; }
    else if (bx < 80) { Ah = xkh; Al = xkl; Bh = wkh; Bl = wkl; arow0 = (bx - 64) * 128; seg = 1; }
    else              { Ah = xvb; Al = xvb; Bh = wvb; Bl = wvb; arow0 = (bx - 80) * 128; seg = 2; }
    const bool split = (seg != 2);

    const int tid  = threadIdx.x;
    const int lane = tid & 63, wv = tid >> 6;
    const int wr = (wv >> 1) * 64, wc = (wv & 1) * 64;
    const int j0 = blockIdx.y * 128;

    floatx4 acc[4][4];
#pragma unroll
    for (int i = 0; i < 4; i++)
#pragma unroll
        for (int j = 0; j < 4; j++) acc[i][j] = {0.f, 0.f, 0.f, 0.f};

    // staging geometry: wave wv owns rows [32wv, 32wv+32); per gll16, lane l
    // covers row +(l>>2), element (l&3)*8 — matches HW lane*16B linear dest.
    const int lrow = lane >> 2;
    const int lch  = (lane & 3) * 8;
    const int grow = 32 * wv;              // wave-uniform row base
    const long gA0 = (long)(arow0 + grow + lrow) * 512 + lch;
    const long gB0 = (long)(j0    + grow + lrow) * 512 + lch;

    const int fr = lane & 15, fq = (lane >> 4) * 8;

#define QKV_STAGE(d, k0) do {                                                 \
        short* bb = LB + (d) * 16384;                                         \
        gll16(Ah + gA0 + (k0),            bb + grow * 32);                    \
        gll16(Ah + gA0 + (k0) + 16 * 512, bb + (grow + 16) * 32);             \
        gll16(Bh + gB0 + (k0),            bb + 8192 + grow * 32);             \
        gll16(Bh + gB0 + (k0) + 16 * 512, bb + 8192 + (grow + 16) * 32);      \
        if (split) {                                                          \
            gll16(Al + gA0 + (k0),            bb + 4096 + grow * 32);         \
            gll16(Al + gA0 + (k0) + 16 * 512, bb + 4096 + (grow + 16) * 32);  \
            gll16(Bl + gB0 + (k0),            bb + 12288 + grow * 32);        \
            gll16(Bl + gB0 + (k0) + 16 * 512, bb + 12288 + (grow + 16) * 32); \
        }                                                                     \
    } while (0)

    QKV_STAGE(0, 0);
    __syncthreads();                        // tile 0 ready

#pragma unroll 2
    for (int t = 0; t < 16; t++) {
        const int cur = t & 1;
        if (t < 15) QKV_STAGE(cur ^ 1, (t + 1) * 32);   // issue-early
        const short* base = LB + cur * 16384;
        short8 ah[4], bh[4];
#pragma unroll
        for (int i = 0; i < 4; i++)
            ah[i] = *(const short8*)&base[(wr + i * 16 + fr) * 32 + fq];
#pragma unroll
        for (int j = 0; j < 4; j++)
            bh[j] = *(const short8*)&base[8192 + (wc + j * 16 + fr) * 32 + fq];
        if (split) {
            short8 al[4], bl[4];
#pragma unroll
            for (int i = 0; i < 4; i++)
                al[i] = *(const short8*)&base[4096 + (wr + i * 16 + fr) * 32 + fq];
#pragma unroll
            for (int j = 0; j < 4; j++)
                bl[j] = *(const short8*)&base[12288 + (wc + j * 16 + fr) * 32 + fq];
#pragma unroll
            for (int i = 0; i < 4; i++)
#pragma unroll
                for (int j = 0; j < 4; j++) {
                    acc[i][j] = __builtin_amdgcn_mfma_f32_16x16x32_bf16(ah[i], bh[j], acc[i][j], 0, 0, 0);
                    acc[i][j] = __builtin_amdgcn_mfma_f32_16x16x32_bf16(ah[i], bl[j], acc[i][j], 0, 0, 0);
                    acc[i][j] = __builtin_amdgcn_mfma_f32_16x16x32_bf16(al[i], bh[j], acc[i][j], 0, 0, 0);
                }
        } else {
#pragma unroll
            for (int i = 0; i < 4; i++)
#pragma unroll
                for (int j = 0; j < 4; j++)
                    acc[i][j] = __builtin_amdgcn_mfma_f32_16x16x32_bf16(ah[i], bh[j], acc[i][j], 0, 0, 0);
        }
        __syncthreads();                    // drain-late: vmcnt after compute
    }
#undef QKV_STAGE

    const int cr = (lane >> 4) * 4, cc = lane & 15;
    if (seg == 2) {
        // LDS transpose: S2[c_local][k'_local], rows padded to 136 shorts
        short (*S2)[136] = (short(*)[136])LB;
#pragma unroll
        for (int i = 0; i < 4; i++)
#pragma unroll
            for (int j = 0; j < 4; j++)
#pragma unroll
                for (int r = 0; r < 4; r++)
                    S2[wc + j * 16 + cc][wr + i * 16 + cr + r] =
                        (short)f2bf(acc[i][j][r]);
        __syncthreads();
        const int orow = tid >> 1;            // c_local 0..127
        const int os   = (tid & 1) * 64;      // k'_local chunk
        unsigned short* dst = vt + (long)(arow0 >> 8) * 131072
                            + (long)(j0 + orow) * 256 + (arow0 & 255) + os;
#pragma unroll
        for (int c8 = 0; c8 < 8; c8++)
            *(short8*)(dst + c8 * 8) = *(const short8*)&S2[orow][os + c8 * 8];
    } else {
#pragma unroll
        for (int i = 0; i < 4; i++)
#pragma unroll
            for (int j = 0; j < 4; j++) {
                const int gj = j0 + wc + j * 16 + cc;
#pragma unroll
                for (int r = 0; r < 4; r++) {
                    const int gi = arow0 + wr + i * 16 + cr + r;
                    const float v = acc[i][j][r];
                    const unsigned short h = f2bf(v);
                    const unsigned short lo = f2bf(v - bf2f(h));
                    if (seg == 0) {
                        const long orow = (long)((gi & 7) * 1024 + ((gi >> 3) & 15) * 64 + (gi >> 7));
                        qh[orow * 512 + gj] = h;
                        ql[orow * 512 + gj] = lo;
                    } else {
                        kh[(long)gi * 512 + gj] = h;
                        kl[(long)gi * 512 + gj] = lo;
                    }
                }
            }
    }
}

// ---------------------------------------------------------------------------
// sim GEMM, 64x64 tiles (512 blocks), bf16x3 on split pairs, epilogue scale
// rs_k[i]*rs_q[j].
// ---------------------------------------------------------------------------
__global__ __launch_bounds__(256) void gemm_sim64(
    const short* __restrict__ Ah, const short* __restrict__ Al,
    const short* __restrict__ Bh, const short* __restrict__ Bl,
    float* __restrict__ Out, const float* __restrict__ rs)
{
    const int z = blockIdx.z;
    Ah += (long)z * 131072;  Al += (long)z * 131072;
    Bh += (long)z * 524288;  Bl += (long)z * 524288;
    Out += (long)z * 262144;
    const float* rsq = rs + (long)z * 1024;
    const float* rsk = rs + 8192 + (long)z * 256;

    __shared__ __align__(16) short Ash[64][40];
    __shared__ __align__(16) short Asl[64][40];
    __shared__ __align__(16) short Bsh[64][40];
    __shared__ __align__(16) short Bsl[64][40];

    const int tid  = threadIdx.x;
    const int lane = tid & 63, wv = tid >> 6;
    const int wr = (wv >> 1) * 32, wc = (wv & 1) * 32;
    const int i0 = blockIdx.x * 64, j0 = blockIdx.y * 64;

    floatx4 acc[2][2];
#pragma unroll
    for (int i = 0; i < 2; i++)
#pragma unroll
        for (int j = 0; j < 2; j++) acc[i][j] = {0.f, 0.f, 0.f, 0.f};

    const int sr = tid >> 2, sch = (tid & 3) * 8;
    const int fr = lane & 15, fq = (lane >> 4) * 8;

    for (int k0 = 0; k0 < 512; k0 += 32) {
        const long ao = (long)(i0 + sr) * 512 + k0 + sch;
        const long bo = (long)(j0 + sr) * 512 + k0 + sch;
        *(short8*)&Ash[sr][sch] = *(const short8*)(Ah + ao);
        *(short8*)&Asl[sr][sch] = *(const short8*)(Al + ao);
        *(short8*)&Bsh[sr][sch] = *(const short8*)(Bh + bo);
        *(short8*)&Bsl[sr][sch] = *(const short8*)(Bl + bo);
        __syncthreads();
        short8 ah[2], al[2], bh[2], bl[2];
#pragma unroll
        for (int i = 0; i < 2; i++) {
            ah[i] = *(const short8*)&Ash[wr + i * 16 + fr][fq];
            al[i] = *(const short8*)&Asl[wr + i * 16 + fr][fq];
        }
#pragma unroll
        for (int j = 0; j < 2; j++) {
            bh[j] = *(const short8*)&Bsh[wc + j * 16 + fr][fq];
            bl[j] = *(const short8*)&Bsl[wc + j * 16 + fr][fq];
        }
#pragma unroll
        for (int i = 0; i < 2; i++)
#pragma unroll
            for (int j = 0; j < 2; j++) {
                acc[i][j] = __builtin_amdgcn_mfma_f32_16x16x32_bf16(ah[i], bh[j], acc[i][j], 0, 0, 0);
                acc[i][j] = __builtin_amdgcn_mfma_f32_16x16x32_bf16(ah[i], bl[j], acc[i][j], 0, 0, 0);
                acc[i][j] = __builtin_amdgcn_mfma_f32_16x16x32_bf16(al[i], bh[j], acc[i][j], 0, 0, 0);
            }
        __syncthreads();
    }

    const int cr = (lane >> 4) * 4, cc = lane & 15;
#pragma unroll
    for (int i = 0; i < 2; i++)
#pragma unroll
        for (int j = 0; j < 2; j++) {
            const int gj = j0 + wc + j * 16 + cc;
            const float sq = rsq[gj];
#pragma unroll
            for (int r = 0; r < 4; r++) {
                const int gi = i0 + wr + i * 16 + cr + r;
                Out[(long)gi * 1024 + gj] = acc[i][j][r] * rsk[gi] * sq;
            }
        }
}

// ---------------------------------------------------------------------------
// Plain bf16 MFMA GEMM (T@V and final proj), 128x128, BK=32, pure bf16.
// ---------------------------------------------------------------------------
template <bool BIAS, bool OPERM, bool OUT_BF16>
__global__ __launch_bounds__(256) void gemm_bf16(
    const short* __restrict__ A, const short* __restrict__ B,
    const float* __restrict__ bias, void* __restrict__ OutV,
    int Kdim, int lda, int ldb, int ldo, long sA, long sB, long sO)
{
    __shared__ __align__(16) short As[128][40];
    __shared__ __align__(16) short Bs[128][40];

    const int tid  = threadIdx.x;
    const int lane = tid & 63, wv = tid >> 6;
    const int wr = (wv >> 1) * 64, wc = (wv & 1) * 64;
    const int i0 = blockIdx.x * 128, j0 = blockIdx.y * 128;

    floatx4 acc[4][4];
#pragma unroll
    for (int i = 0; i < 4; i++)
#pragma unroll
        for (int j = 0; j < 4; j++) acc[i][j] = {0.f, 0.f, 0.f, 0.f};

    const int sr = tid >> 2, sk = (tid & 3) * 8;
    const int fr = lane & 15, fq = (lane >> 4) * 8;
    const short* pa = A + (long)blockIdx.z * sA;
    const short* pb = B + (long)blockIdx.z * sB;

    for (int k0 = 0; k0 < Kdim; k0 += 32) {
#pragma unroll
        for (int p = 0; p < 2; p++) {
            *(short8*)&As[sr + p * 64][sk] =
                *(const short8*)(pa + (long)(i0 + sr + p * 64) * lda + k0 + sk);
            *(short8*)&Bs[sr + p * 64][sk] =
                *(const short8*)(pb + (long)(j0 + sr + p * 64) * ldb + k0 + sk);
        }
        __syncthreads();
        short8 af[4], bf[4];
#pragma unroll
        for (int i = 0; i < 4; i++) af[i] = *(const short8*)&As[wr + i * 16 + fr][fq];
#pragma unroll
        for (int j = 0; j < 4; j++) bf[j] = *(const short8*)&Bs[wc + j * 16 + fr][fq];
#pragma unroll
        for (int i = 0; i < 4; i++)
#pragma unroll
            for (int j = 0; j < 4; j++)
                acc[i][j] = __builtin_amdgcn_mfma_f32_16x16x32_bf16(af[i], bf[j], acc[i][j], 0, 0, 0);
        __syncthreads();
    }

    float* Of = nullptr; unsigned short* Ob = nullptr;
    if constexpr (OUT_BF16) Ob = (unsigned short*)OutV + (long)blockIdx.z * sO;
    else                    Of = (float*)OutV + (long)blockIdx.z * sO;
    const int cr = (lane >> 4) * 4, cc = lane & 15;
#pragma unroll
    for (int i = 0; i < 4; i++) {
#pragma unroll
        for (int j = 0; j < 4; j++) {
            const int gj = j0 + wc + j * 16 + cc;
            float bb = 0.0f;
            if constexpr (BIAS) bb = bias[gj];
#pragma unroll
            for (int r = 0; r < 4; r++) {
                const int gi = i0 + wr + i * 16 + cr + r;
                float v = acc[i][j][r] + bb;
                long idx;
                if constexpr (OPERM)
                    idx = (long)((gi & 63) * 128 + ((gi >> 6) & 15) * 8 + (gi >> 10)) * ldo + gj;
                else
                    idx = (long)gi * ldo + gj;
                if constexpr (OUT_BF16) Ob[idx] = f2bf(v);
                else                    Of[idx] = v;
            }
        }
    }
}

// ---------------------------------------------------------------------------
// Row reciprocal-norms from split pairs: rows 0..8191 q, 8192..10239 k.
// ---------------------------------------------------------------------------
__global__ __launch_bounds__(256) void rownorm(
    const unsigned short* __restrict__ qh, const unsigned short* __restrict__ ql,
    const unsigned short* __restrict__ kh, const unsigned short* __restrict__ kl,
    float* __restrict__ rs)
{
    const int row  = blockIdx.x * 4 + (threadIdx.x >> 6);
    const int lane = threadIdx.x & 63;
    const unsigned short *ph, *pl;
    long r;
    if (row < 8192) { ph = qh; pl = ql; r = row; }
    else            { ph = kh; pl = kl; r = row - 8192; }
    const long o = r * 512 + lane * 8;
    ushort4 h0 = *(const ushort4*)(ph + o), h1 = *(const ushort4*)(ph + o + 4);
    ushort4 l0 = *(const ushort4*)(pl + o), l1 = *(const ushort4*)(pl + o + 4);
    float ss = 0.0f;
    const unsigned short hv[8] = {h0.x, h0.y, h0.z, h0.w, h1.x, h1.y, h1.z, h1.w};
    const unsigned short lv[8] = {l0.x, l0.y, l0.z, l0.w, l1.x, l1.y, l1.z, l1.w};
#pragma unroll
    for (int i = 0; i < 8; i++) {
        const float v = bf2f(hv[i]) + bf2f(lv[i]);
        ss = fmaf(v, v, ss);
    }
#pragma unroll
    for (int off = 32; off; off >>= 1) ss += __shfl_xor(ss, off, 64);
    if (lane == 0) rs[row] = 1.0f / fmaxf(sqrtf(ss), 1e-12f);
}

// ---------------------------------------------------------------------------
// Sinkhorn, rotated dual layouts + DPP + permlane butterflies + early exit.
// ---------------------------------------------------------------------------
__global__ __launch_bounds__(256, 2) void sinkhorn5(
    const float* __restrict__ sim, float* __restrict__ score,
    unsigned short* __restrict__ Tt)
{
    const int lane = threadIdx.x & 63;
    const int bk   = blockIdx.x * 4 + (threadIdx.x >> 6);
    const float* S = sim + (long)bk * 1024;
    const int m = lane & 15, g = lane >> 4;

    int idx[16];
    idx[0] = m;
    idx[1]  = RRI(m, 0x121); idx[2]  = RRI(m, 0x122); idx[3]  = RRI(m, 0x123);
    idx[4]  = RRI(m, 0x124); idx[5]  = RRI(m, 0x125); idx[6]  = RRI(m, 0x126);
    idx[7]  = RRI(m, 0x127); idx[8]  = RRI(m, 0x128); idx[9]  = RRI(m, 0x129);
    idx[10] = RRI(m, 0x12a); idx[11] = RRI(m, 0x12b); idx[12] = RRI(m, 0x12c);
    idx[13] = RRI(m, 0x12d); idx[14] = RRI(m, 0x12e); idx[15] = RRI(m, 0x12f);

    float K1[16], K2R[16], sv[16];
#pragma unroll
    for (int j = 0; j < 16; j++) {
        K1[j] = __expf((S[m * 64 + g * 16 + idx[j]] - 1.0f) * 20.0f);
        const float s_ = S[idx[j] * 64 + lane];
        sv[j]  = s_;
        K2R[j] = __expf((s_ - 1.0f) * 20.0f);
    }

    const float muP = 0.0625f + 1e-8f;
    const float nuP = 0.015625f + 1e-8f;
    float b = 1.0f;
    float aB[16], bB[16];
#pragma unroll
    for (int j = 0; j < 16; j++) bB[j] = 1.0f;

#pragma unroll 1
    for (int it = 0; it < 100; it++) {
        float s0 = 0, s1 = 0, s2 = 0, s3 = 0;
#pragma unroll
        for (int j = 0; j < 4; j++) {
            s0 = fmaf(K1[j],      bB[j],      s0);
            s1 = fmaf(K1[4 + j],  bB[4 + j],  s1);
            s2 = fmaf(K1[8 + j],  bB[8 + j],  s2);
            s3 = fmaf(K1[12 + j], bB[12 + j], s3);
        }
        float s = (s0 + s1) + (s2 + s3);
        s = xadd16(s);
        s = xadd32(s);
        const float a = muP * fastrcp(s);
        GATH16(aB, a);
        float t0 = 0, t1 = 0, t2 = 0, t3 = 0;
#pragma unroll
        for (int j = 0; j < 4; j++) {
            t0 = fmaf(K2R[j],      aB[j],      t0);
            t1 = fmaf(K2R[4 + j],  aB[4 + j],  t1);
            t2 = fmaf(K2R[8 + j],  aB[8 + j],  t2);
            t3 = fmaf(K2R[12 + j], aB[12 + j], t3);
        }
        const float bp_ = b;
        b = nuP * fastrcp((t0 + t1) + (t2 + t3));
        GATH16(bB, b);
        const int conv = __builtin_fabsf(b - bp_) <= 1e-5f * __builtin_fabsf(b);
        if (__all(conv)) break;
    }

    float* Sc = score + (long)bk * 1024;
    unsigned short* Tp = Tt + (long)(bk >> 8) * 262144 + (bk & 255);
#pragma unroll
    for (int j = 0; j < 16; j++) {
        const int row = idx[j];
        const float Tv = aB[j] * K2R[j] * b;
        Sc[row * 64 + lane] = 1024.0f * sv[j] * Tv;
        Tp[(long)(row * 64 + lane) * 256] = f2bf(Tv);
    }
}

extern "C" void kernel_launch(void* const* d_in, const int* in_sizes, int n_in,
                              void* d_out, int out_size, void* d_ws, size_t ws_size,
                              hipStream_t stream)
{
    (void)in_sizes; (void)n_in; (void)out_size; (void)ws_size;
    const float* xq = (const float*)d_in[0];
    const float* xk = (const float*)d_in[1];
    const float* xv = (const float*)d_in[2];
    const float* Wq = (const float*)d_in[3];
    const float* Wk = (const float*)d_in[4];
    const float* Wv = (const float*)d_in[5];
    const float* Wp = (const float*)d_in[6];
    const float* bp = (const float*)d_in[7];

    float* out_x     = (float*)d_out;           // (Nq,M,B,C) = 8192 x 512
    float* out_score = out_x + 8192L * 512;     // (B,K,M,Nq) = 2048 x 1024

    // workspace (47.1 MB of the proven 48 MB); regions reused across phases
    char* W = (char*)d_ws;
    const long MB = 1 << 20;
    unsigned short* qh   = (unsigned short*)(W + 0);        // 8MB [b][mn][c]
    unsigned short* ql   = (unsigned short*)(W + 8 * MB);   // 8MB
    unsigned short* xq_h = (unsigned short*)(W + 16 * MB);  // 8MB, dead after qkv
    float*          simb = (float*)(W + 16 * MB);           // 8MB (reuse)
    unsigned short* xq_l = (unsigned short*)(W + 24 * MB);  // 8MB, dead after qkv
    unsigned short* xpre = (unsigned short*)(W + 24 * MB);  // 8MB (reuse)
    unsigned short* xk_h = (unsigned short*)(W + 32 * MB);  // 2MB, dead after qkv
    unsigned short* xk_l = (unsigned short*)(W + 34 * MB);  // 2MB
    unsigned short* Tt   = (unsigned short*)(W + 32 * MB);  // 4MB (reuse)
    unsigned short* xv_b = (unsigned short*)(W + 36 * MB);  // 2MB
    unsigned short* kh   = (unsigned short*)(W + 38 * MB);  // 2MB [b][k'][c]
    unsigned short* kl   = (unsigned short*)(W + 40 * MB);  // 2MB
    unsigned short* vt   = (unsigned short*)(W + 42 * MB);  // 2MB [b][c][k']
    unsigned short* wqh  = (unsigned short*)(W + 44 * MB);
    unsigned short* wql  = (unsigned short*)(W + 44 * MB + 1 * 524288);
    unsigned short* wkh  = (unsigned short*)(W + 44 * MB + 2 * 524288);
    unsigned short* wkl  = (unsigned short*)(W + 44 * MB + 3 * 524288);
    unsigned short* wvb  = (unsigned short*)(W + 44 * MB + 4 * 524288);
    unsigned short* wpb  = (unsigned short*)(W + 44 * MB + 5 * 524288);
    float*          rs   = (float*)(W + 47 * MB);           // 40KB

    const dim3 blk(256);

    // 1: precast/split all fp32 operands (memory-bound, one dispatch)
    prep<<<7168, blk, 0, stream>>>(xq, xk, xv, Wq, Wk, Wv, Wp,
                                   xq_h, xq_l, xk_h, xk_l, xv_b,
                                   wqh, wql, wkh, wkl, wvb, wpb);

    // 2: fused q/k/v projections (128x128, gll_lds double-buffered 2-phase)
    gemm_qkv2<<<dim3(96, 4), blk, 0, stream>>>(
        xq_h, xq_l, xk_h, xk_l, xv_b, wqh, wql, wkh, wkl, wvb,
        qh, ql, kh, kl, vt);

    // 3: reciprocal row norms
    rownorm<<<2560, blk, 0, stream>>>(qh, ql, kh, kl, rs);

    // 4: sim[b][k'][mn] = (k.q) * rs_k * rs_q
    gemm_sim64<<<dim3(4, 16, 8), blk, 0, stream>>>(
        (const short*)kh, (const short*)kl, (const short*)qh, (const short*)ql,
        simb, rs);

    // 5: Sinkhorn -> score (out) + T bf16 [b][mn][k']
    sinkhorn5<<<512, blk, 0, stream>>>(simb, out_score, Tt);

    // 6: xpre[b][mn][c] = sum_k' T[b][mn][k'] * v[b][k'][c]
    gemm_bf16<false, false, true><<<dim3(8, 4, 8), blk, 0, stream>>>(
        (const short*)Tt, (const short*)vt, nullptr, xpre,
        256, 256, 256, 512, 262144, 131072, 524288);

    // 7: x = xpre @ Wp^T + bp, rows (b,mn)->(n,m,b), fp32 out
    gemm_bf16<true, true, false><<<dim3(64, 4), blk, 0, stream>>>(
        (const short*)xpre, (const short*)wpb, bp, out_x,
        512, 512, 512, 512, 0, 0, 0);
}

// Round 6
// 186.834 us; speedup vs baseline: 1.0711x; 1.0105x over previous
//
#include <hip/hip_runtime.h>

// ---------------------------------------------------------------------------
// AttentionOT  (Nq=64, M=16, B=8, K=256, C=512)
//   Front (error-critical, feeds exp(20*sim)): bf16x3 split MFMA (Markidis),
//     operands PRE-SPLIT by a memory-bound prep pass.
//   Back half: plain bf16 MFMA, weights precast.
//   Sinkhorn (round 6): launch_bounds(256,2), permlane16/32 butterflies,
//     fixed-point early exit.  (verified: 49us -> out of top-5)
//   qkv GEMM (round 11): 64x128 tiles, gll_lds dbuf 2-phase. 768 blocks =
//     EXACTLY 3/CU (all resident, zero tail; m97 operating point). Round-2's
//     64x128 regression causes are absent: no reg-staging (gll_lds, VGPR~100),
//     proven grid order (bx=tile, by=jslice), launch_bounds(256,3).
//   rownorm (round 11): FUSED into sim64 — staging threads accumulate
//     sum-of-squares in registers, quad shfl_xor reduce, LDS broadcast.
//     One fewer dispatch + 20MB fewer reads.
//   6 dispatches: prep -> qkv -> sim -> sinkhorn -> T@V -> proj.
// ---------------------------------------------------------------------------

typedef short   short8  __attribute__((ext_vector_type(8)));
typedef float   floatx4 __attribute__((ext_vector_type(4)));
typedef unsigned int uint2e __attribute__((ext_vector_type(2)));

static __device__ __forceinline__ float fastrcp(float x) {
    return __builtin_amdgcn_rcpf(x);
}
static __device__ __forceinline__ unsigned short f2bf(float f) {
    union { float f; unsigned u; } c; c.f = f;
    unsigned r = c.u + 0x7FFF + ((c.u >> 16) & 1);   // RNE
    return (unsigned short)(r >> 16);
}
static __device__ __forceinline__ float bf2f(unsigned short h) {
    union { unsigned u; float f; } c; c.u = (unsigned)h << 16;
    return c.f;
}

// HBM -> LDS direct DMA, 16B per lane. LDS dest is wave-uniform base;
// HW writes lane i at base + i*16 (m03/m97/m104).
static __device__ __forceinline__ void gll16(const unsigned short* g, short* l) {
    __builtin_amdgcn_global_load_lds(
        (const __attribute__((address_space(1))) void*)g,
        (__attribute__((address_space(3))) void*)l, 16, 0, 0);
}

// Cross-lane butterfly adds via gfx950 permlane16/32_swap (full-rate VALU,
// vs ~120cyc ds_bpermute for shfl_xor).
#if __has_builtin(__builtin_amdgcn_permlane16_swap)
static __device__ __forceinline__ float xadd16(float s) {
    uint2e r = __builtin_amdgcn_permlane16_swap(
        __float_as_uint(s), __float_as_uint(s), false, false);
    return __uint_as_float(r.x) + __uint_as_float(r.y);
}
#else
static __device__ __forceinline__ float xadd16(float s) {
    return s + __shfl_xor(s, 16, 64);
}
#endif
#if __has_builtin(__builtin_amdgcn_permlane32_swap)
static __device__ __forceinline__ float xadd32(float s) {
    uint2e r = __builtin_amdgcn_permlane32_swap(
        __float_as_uint(s), __float_as_uint(s), false, false);
    return __uint_as_float(r.x) + __uint_as_float(r.y);
}
#else
static __device__ __forceinline__ float xadd32(float s) {
    return s + __shfl_xor(s, 32, 64);
}
#endif

#define RRI(x, C) __builtin_amdgcn_update_dpp(0, (x), (C), 0xf, 0xf, true)
#define RRF(x, C) __int_as_float(RRI(__float_as_int(x), (C)))
#define GATH16(d, s) do { d[0] = (s);                                        \
    d[1]  = RRF((s), 0x121); d[2]  = RRF((s), 0x122);                        \
    d[3]  = RRF((s), 0x123); d[4]  = RRF((s), 0x124);                        \
    d[5]  = RRF((s), 0x125); d[6]  = RRF((s), 0x126);                        \
    d[7]  = RRF((s), 0x127); d[8]  = RRF((s), 0x128);                        \
    d[9]  = RRF((s), 0x129); d[10] = RRF((s), 0x12a);                        \
    d[11] = RRF((s), 0x12b); d[12] = RRF((s), 0x12c);                        \
    d[13] = RRF((s), 0x12d); d[14] = RRF((s), 0x12e);                        \
    d[15] = RRF((s), 0x12f); } while (0)

// ---------------------------------------------------------------------------
// prep: fp32 -> bf16 split (xq,xk,Wq,Wk) / cast (xv,Wv,Wp).  One dispatch,
// one float4 per thread, memory-bound.
// ---------------------------------------------------------------------------
__global__ __launch_bounds__(256) void prep(
    const float* __restrict__ xq, const float* __restrict__ xk,
    const float* __restrict__ xv, const float* __restrict__ Wq,
    const float* __restrict__ Wk, const float* __restrict__ Wv,
    const float* __restrict__ Wp,
    unsigned short* __restrict__ xqh, unsigned short* __restrict__ xql,
    unsigned short* __restrict__ xkh, unsigned short* __restrict__ xkl,
    unsigned short* __restrict__ xvb,
    unsigned short* __restrict__ wqh, unsigned short* __restrict__ wql,
    unsigned short* __restrict__ wkh, unsigned short* __restrict__ wkl,
    unsigned short* __restrict__ wvb, unsigned short* __restrict__ wpb)
{
    const int b = blockIdx.x;
    const float* src; unsigned short *dh, *dl; long base;
    if (b < 4096)      { src = xq; dh = xqh; dl = xql;     base = (long)b * 256; }
    else if (b < 5120) { src = xk; dh = xkh; dl = xkl;     base = (long)(b - 4096) * 256; }
    else if (b < 6144) { src = xv; dh = xvb; dl = nullptr; base = (long)(b - 5120) * 256; }
    else if (b < 6400) { src = Wq; dh = wqh; dl = wql;     base = (long)(b - 6144) * 256; }
    else if (b < 6656) { src = Wk; dh = wkh; dl = wkl;     base = (long)(b - 6400) * 256; }
    else if (b < 6912) { src = Wv; dh = wvb; dl = nullptr; base = (long)(b - 6656) * 256; }
    else               { src = Wp; dh = wpb; dl = nullptr; base = (long)(b - 6912) * 256; }
    const long i = base + threadIdx.x;
    float4 v = ((const float4*)src)[i];
    ushort4 h;
    h.x = f2bf(v.x); h.y = f2bf(v.y); h.z = f2bf(v.z); h.w = f2bf(v.w);
    ((ushort4*)dh)[i] = h;
    if (dl) {
        ushort4 l;
        l.x = f2bf(v.x - bf2f(h.x)); l.y = f2bf(v.y - bf2f(h.y));
        l.z = f2bf(v.z - bf2f(h.z)); l.w = f2bf(v.w - bf2f(h.w));
        ((ushort4*)dl)[i] = l;
    }
}

// ---------------------------------------------------------------------------
// Fused q/k/v projection on PRECONVERTED bf16 operands.  64x128 tiles,
// BK=32, 768 blocks (exactly 3/CU).  blockIdx.x: 0..127 q (split3),
// 128..159 k (split3), 160..191 v (plain); blockIdx.y = j0 slice.
// gll_lds width-16 staging, LDS double buffer (2 x 24KB linear), 2-phase:
// stage tile t+1 -> compute tile t -> one __syncthreads.
// Per buffer: Ah[64][32]@0, Al@2048, Bh[128][32]@4096, Bl@8192 (shorts).
// Epilogues: q -> qh/ql permuted rows; k -> kh/kl; v -> vt[b][c][k'] via
// LDS transpose (coalesced 16B stores).
// ---------------------------------------------------------------------------
__global__ __launch_bounds__(256, 3) void gemm_qkv2(
    const unsigned short* __restrict__ xqh, const unsigned short* __restrict__ xql,
    const unsigned short* __restrict__ xkh, const unsigned short* __restrict__ xkl,
    const unsigned short* __restrict__ xvb,
    const unsigned short* __restrict__ wqh, const unsigned short* __restrict__ wql,
    const unsigned short* __restrict__ wkh, const unsigned short* __restrict__ wkl,
    const unsigned short* __restrict__ wvb,
    unsigned short* __restrict__ qh, unsigned short* __restrict__ ql,
    unsigned short* __restrict__ kh, unsigned short* __restrict__ kl,
    unsigned short* __restrict__ vt)
{
    __shared__ __align__(16) short LB[24576];          // 48 KB (2 x 24KB)

    const int bt = blockIdx.x;
    const unsigned short *Ah, *Al, *Bh, *Bl;
    int seg, arow0;
    if (bt < 128)      { Ah = xqh; Al = xql; Bh = wqh; Bl = wql; arow0 = bt * 64;         seg = 0; }
    else if (bt < 160) { Ah = xkh; Al = xkl; Bh = wkh; Bl = wkl; arow0 = (bt - 128) * 64; seg = 1; }
    else               { Ah = xvb; Al = xvb; Bh = wvb; Bl = wvb; arow0 = (bt - 160) * 64; seg = 2; }
    const bool split = (seg != 2);

    const int tid  = threadIdx.x;
    const int lane = tid & 63, wv = tid >> 6;
    const int wc = wv * 32;                            // wave col slice
    const int j0 = blockIdx.y * 128;

    floatx4 acc[4][2];
#pragma unroll
    for (int i = 0; i < 4; i++)
#pragma unroll
        for (int j = 0; j < 2; j++) acc[i][j] = {0.f, 0.f, 0.f, 0.f};

    // staging: wave wv owns A rows [16wv,16wv+16) (1 DMA x2 arrays) and
    // B rows [32wv,32wv+32) (2 DMAs x2 arrays). Lane l covers row +(l>>2),
    // element (l&3)*8 — matches HW linear lane*16B dest.
    const int lrow = lane >> 2;
    const int lch  = (lane & 3) * 8;
    const int gra  = 16 * wv;                          // A wave row base
    const int grb  = 32 * wv;                          // B wave row base
    const long gA0 = (long)(arow0 + gra + lrow) * 512 + lch;
    const long gB0 = (long)(j0    + grb + lrow) * 512 + lch;

    const int fr = lane & 15, fq = (lane >> 4) * 8;

#define QKV_STAGE(d, k0) do {                                                 \
        short* bb = LB + (d) * 12288;                                         \
        gll16(Ah + gA0 + (k0),            bb + gra * 32);                     \
        gll16(Bh + gB0 + (k0),            bb + 4096 + grb * 32);              \
        gll16(Bh + gB0 + (k0) + 16 * 512, bb + 4096 + (grb + 16) * 32);       \
        if (split) {                                                          \
            gll16(Al + gA0 + (k0),            bb + 2048 + gra * 32);          \
            gll16(Bl + gB0 + (k0),            bb + 8192 + grb * 32);          \
            gll16(Bl + gB0 + (k0) + 16 * 512, bb + 8192 + (grb + 16) * 32);   \
        }                                                                     \
    } while (0)

    QKV_STAGE(0, 0);
    __syncthreads();                        // tile 0 ready

#pragma unroll 2
    for (int t = 0; t < 16; t++) {
        const int cur = t & 1;
        if (t < 15) QKV_STAGE(cur ^ 1, (t + 1) * 32);   // issue-early
        const short* base = LB + cur * 12288;
        short8 ah[4], bh[2];
#pragma unroll
        for (int i = 0; i < 4; i++)
            ah[i] = *(const short8*)&base[(i * 16 + fr) * 32 + fq];
#pragma unroll
        for (int j = 0; j < 2; j++)
            bh[j] = *(const short8*)&base[4096 + (wc + j * 16 + fr) * 32 + fq];
        if (split) {
            short8 al[4], bl[2];
#pragma unroll
            for (int i = 0; i < 4; i++)
                al[i] = *(const short8*)&base[2048 + (i * 16 + fr) * 32 + fq];
#pragma unroll
            for (int j = 0; j < 2; j++)
                bl[j] = *(const short8*)&base[8192 + (wc + j * 16 + fr) * 32 + fq];
#pragma unroll
            for (int i = 0; i < 4; i++)
#pragma unroll
                for (int j = 0; j < 2; j++) {
                    acc[i][j] = __builtin_amdgcn_mfma_f32_16x16x32_bf16(ah[i], bh[j], acc[i][j], 0, 0, 0);
                    acc[i][j] = __builtin_amdgcn_mfma_f32_16x16x32_bf16(ah[i], bl[j], acc[i][j], 0, 0, 0);
                    acc[i][j] = __builtin_amdgcn_mfma_f32_16x16x32_bf16(al[i], bh[j], acc[i][j], 0, 0, 0);
                }
        } else {
#pragma unroll
            for (int i = 0; i < 4; i++)
#pragma unroll
                for (int j = 0; j < 2; j++)
                    acc[i][j] = __builtin_amdgcn_mfma_f32_16x16x32_bf16(ah[i], bh[j], acc[i][j], 0, 0, 0);
        }
        __syncthreads();                    // drain-late: vmcnt after compute
    }
#undef QKV_STAGE

    const int cr = (lane >> 4) * 4, cc = lane & 15;
    if (seg == 2) {
        // LDS transpose: S2[c_local][k'_local], rows padded to 72 shorts
        short (*S2)[72] = (short(*)[72])LB;            // 128 x 72 = 18 KB
#pragma unroll
        for (int i = 0; i < 4; i++)
#pragma unroll
            for (int j = 0; j < 2; j++)
#pragma unroll
                for (int r = 0; r < 4; r++)
                    S2[wc + j * 16 + cc][i * 16 + cr + r] =
                        (short)f2bf(acc[i][j][r]);
        __syncthreads();
        const int orow = tid >> 1;            // c_local 0..127
        const int os   = (tid & 1) * 32;      // k'_local chunk
        unsigned short* dst = vt + (long)(arow0 >> 8) * 131072
                            + (long)(j0 + orow) * 256 + (arow0 & 255) + os;
#pragma unroll
        for (int c8 = 0; c8 < 4; c8++)
            *(short8*)(dst + c8 * 8) = *(const short8*)&S2[orow][os + c8 * 8];
    } else {
#pragma unroll
        for (int i = 0; i < 4; i++)
#pragma unroll
            for (int j = 0; j < 2; j++) {
                const int gj = j0 + wc + j * 16 + cc;
#pragma unroll
                for (int r = 0; r < 4; r++) {
                    const int gi = arow0 + i * 16 + cr + r;
                    const float v = acc[i][j][r];
                    const unsigned short h = f2bf(v);
                    const unsigned short lo = f2bf(v - bf2f(h));
                    if (seg == 0) {
                        const long orow = (long)((gi & 7) * 1024 + ((gi >> 3) & 15) * 64 + (gi >> 7));
                        qh[orow * 512 + gj] = h;
                        ql[orow * 512 + gj] = lo;
                    } else {
                        kh[(long)gi * 512 + gj] = h;
                        kl[(long)gi * 512 + gj] = lo;
                    }
                }
            }
    }
}

// ---------------------------------------------------------------------------
// sim GEMM, 64x64 tiles (512 blocks), bf16x3 on split pairs. Round 11:
// row norms computed IN-KERNEL from the staging registers (fused rownorm):
// each staging thread accumulates ssq of its 8-elem chunks across all 16
// K-steps, quad shfl_xor reduce, LDS broadcast, epilogue scale
// rs_k[i]*rs_q[j].
// ---------------------------------------------------------------------------
__global__ __launch_bounds__(256) void gemm_sim64(
    const short* __restrict__ Ah, const short* __restrict__ Al,
    const short* __restrict__ Bh, const short* __restrict__ Bl,
    float* __restrict__ Out)
{
    const int z = blockIdx.z;
    Ah += (long)z * 131072;  Al += (long)z * 131072;
    Bh += (long)z * 524288;  Bl += (long)z * 524288;
    Out += (long)z * 262144;

    __shared__ __align__(16) short Ash[64][40];
    __shared__ __align__(16) short Asl[64][40];
    __shared__ __align__(16) short Bsh[64][40];
    __shared__ __align__(16) short Bsl[64][40];
    __shared__ float sRA[64];
    __shared__ float sRB[64];

    const int tid  = threadIdx.x;
    const int lane = tid & 63, wv = tid >> 6;
    const int wr = (wv >> 1) * 32, wc = (wv & 1) * 32;
    const int i0 = blockIdx.x * 64, j0 = blockIdx.y * 64;

    floatx4 acc[2][2];
#pragma unroll
    for (int i = 0; i < 2; i++)
#pragma unroll
        for (int j = 0; j < 2; j++) acc[i][j] = {0.f, 0.f, 0.f, 0.f};

    const int sr = tid >> 2, sch = (tid & 3) * 8;
    const int fr = lane & 15, fq = (lane >> 4) * 8;

    float ssqA = 0.0f, ssqB = 0.0f;

    for (int k0 = 0; k0 < 512; k0 += 32) {
        const long ao = (long)(i0 + sr) * 512 + k0 + sch;
        const long bo = (long)(j0 + sr) * 512 + k0 + sch;
        const short8 vah = *(const short8*)(Ah + ao);
        const short8 val_ = *(const short8*)(Al + ao);
        const short8 vbh = *(const short8*)(Bh + bo);
        const short8 vbl = *(const short8*)(Bl + bo);
        *(short8*)&Ash[sr][sch] = vah;
        *(short8*)&Asl[sr][sch] = val_;
        *(short8*)&Bsh[sr][sch] = vbh;
        *(short8*)&Bsl[sr][sch] = vbl;
#pragma unroll
        for (int e = 0; e < 8; e++) {
            const float va = bf2f((unsigned short)vah[e]) + bf2f((unsigned short)val_[e]);
            const float vb = bf2f((unsigned short)vbh[e]) + bf2f((unsigned short)vbl[e]);
            ssqA = fmaf(va, va, ssqA);
            ssqB = fmaf(vb, vb, ssqB);
        }
        __syncthreads();
        short8 ah[2], al[2], bh[2], bl[2];
#pragma unroll
        for (int i = 0; i < 2; i++) {
            ah[i] = *(const short8*)&Ash[wr + i * 16 + fr][fq];
            al[i] = *(const short8*)&Asl[wr + i * 16 + fr][fq];
        }
#pragma unroll
        for (int j = 0; j < 2; j++) {
            bh[j] = *(const short8*)&Bsh[wc + j * 16 + fr][fq];
            bl[j] = *(const short8*)&Bsl[wc + j * 16 + fr][fq];
        }
#pragma unroll
        for (int i = 0; i < 2; i++)
#pragma unroll
            for (int j = 0; j < 2; j++) {
                acc[i][j] = __builtin_amdgcn_mfma_f32_16x16x32_bf16(ah[i], bh[j], acc[i][j], 0, 0, 0);
                acc[i][j] = __builtin_amdgcn_mfma_f32_16x16x32_bf16(ah[i], bl[j], acc[i][j], 0, 0, 0);
                acc[i][j] = __builtin_amdgcn_mfma_f32_16x16x32_bf16(al[i], bh[j], acc[i][j], 0, 0, 0);
            }
        __syncthreads();
    }

    // quad reduce (stagers of row sr are lanes tid^1, tid^2 — same quad)
    ssqA += __shfl_xor(ssqA, 1, 64);  ssqA += __shfl_xor(ssqA, 2, 64);
    ssqB += __shfl_xor(ssqB, 1, 64);  ssqB += __shfl_xor(ssqB, 2, 64);
    if ((tid & 3) == 0) {
        sRA[sr] = 1.0f / fmaxf(sqrtf(ssqA), 1e-12f);
        sRB[sr] = 1.0f / fmaxf(sqrtf(ssqB), 1e-12f);
    }
    __syncthreads();

    const int cr = (lane >> 4) * 4, cc = lane & 15;
#pragma unroll
    for (int i = 0; i < 2; i++)
#pragma unroll
        for (int j = 0; j < 2; j++) {
            const int lc = wc + j * 16 + cc;
            const float sq = sRB[lc];
            const int gj = j0 + lc;
#pragma unroll
            for (int r = 0; r < 4; r++) {
                const int lr = wr + i * 16 + cr + r;
                Out[(long)(i0 + lr) * 1024 + gj] = acc[i][j][r] * sRA[lr] * sq;
            }
        }
}

// ---------------------------------------------------------------------------
// Plain bf16 MFMA GEMM (T@V and final proj), 128x128, BK=32, pure bf16.
// ---------------------------------------------------------------------------
template <bool BIAS, bool OPERM, bool OUT_BF16>
__global__ __launch_bounds__(256) void gemm_bf16(
    const short* __restrict__ A, const short* __restrict__ B,
    const float* __restrict__ bias, void* __restrict__ OutV,
    int Kdim, int lda, int ldb, int ldo, long sA, long sB, long sO)
{
    __shared__ __align__(16) short As[128][40];
    __shared__ __align__(16) short Bs[128][40];

    const int tid  = threadIdx.x;
    const int lane = tid & 63, wv = tid >> 6;
    const int wr = (wv >> 1) * 64, wc = (wv & 1) * 64;
    const int i0 = blockIdx.x * 128, j0 = blockIdx.y * 128;

    floatx4 acc[4][4];
#pragma unroll
    for (int i = 0; i < 4; i++)
#pragma unroll
        for (int j = 0; j < 4; j++) acc[i][j] = {0.f, 0.f, 0.f, 0.f};

    const int sr = tid >> 2, sk = (tid & 3) * 8;
    const int fr = lane & 15, fq = (lane >> 4) * 8;
    const short* pa = A + (long)blockIdx.z * sA;
    const short* pb = B + (long)blockIdx.z * sB;

    for (int k0 = 0; k0 < Kdim; k0 += 32) {
#pragma unroll
        for (int p = 0; p < 2; p++) {
            *(short8*)&As[sr + p * 64][sk] =
                *(const short8*)(pa + (long)(i0 + sr + p * 64) * lda + k0 + sk);
            *(short8*)&Bs[sr + p * 64][sk] =
                *(const short8*)(pb + (long)(j0 + sr + p * 64) * ldb + k0 + sk);
        }
        __syncthreads();
        short8 af[4], bf[4];
#pragma unroll
        for (int i = 0; i < 4; i++) af[i] = *(const short8*)&As[wr + i * 16 + fr][fq];
#pragma unroll
        for (int j = 0; j < 4; j++) bf[j] = *(const short8*)&Bs[wc + j * 16 + fr][fq];
#pragma unroll
        for (int i = 0; i < 4; i++)
#pragma unroll
            for (int j = 0; j < 4; j++)
                acc[i][j] = __builtin_amdgcn_mfma_f32_16x16x32_bf16(af[i], bf[j], acc[i][j], 0, 0, 0);
        __syncthreads();
    }

    float* Of = nullptr; unsigned short* Ob = nullptr;
    if constexpr (OUT_BF16) Ob = (unsigned short*)OutV + (long)blockIdx.z * sO;
    else                    Of = (float*)OutV + (long)blockIdx.z * sO;
    const int cr = (lane >> 4) * 4, cc = lane & 15;
#pragma unroll
    for (int i = 0; i < 4; i++) {
#pragma unroll
        for (int j = 0; j < 4; j++) {
            const int gj = j0 + wc + j * 16 + cc;
            float bb = 0.0f;
            if constexpr (BIAS) bb = bias[gj];
#pragma unroll
            for (int r = 0; r < 4; r++) {
                const int gi = i0 + wr + i * 16 + cr + r;
                float v = acc[i][j][r] + bb;
                long idx;
                if constexpr (OPERM)
                    idx = (long)((gi & 63) * 128 + ((gi >> 6) & 15) * 8 + (gi >> 10)) * ldo + gj;
                else
                    idx = (long)gi * ldo + gj;
                if constexpr (OUT_BF16) Ob[idx] = f2bf(v);
                else                    Of[idx] = v;
            }
        }
    }
}

// ---------------------------------------------------------------------------
// Sinkhorn, rotated dual layouts + DPP + permlane butterflies + early exit.
// ---------------------------------------------------------------------------
__global__ __launch_bounds__(256, 2) void sinkhorn5(
    const float* __restrict__ sim, float* __restrict__ score,
    unsigned short* __restrict__ Tt)
{
    const int lane = threadIdx.x & 63;
    const int bk   = blockIdx.x * 4 + (threadIdx.x >> 6);
    const float* S = sim + (long)bk * 1024;
    const int m = lane & 15, g = lane >> 4;

    int idx[16];
    idx[0] = m;
    idx[1]  = RRI(m, 0x121); idx[2]  = RRI(m, 0x122); idx[3]  = RRI(m, 0x123);
    idx[4]  = RRI(m, 0x124); idx[5]  = RRI(m, 0x125); idx[6]  = RRI(m, 0x126);
    idx[7]  = RRI(m, 0x127); idx[8]  = RRI(m, 0x128); idx[9]  = RRI(m, 0x129);
    idx[10] = RRI(m, 0x12a); idx[11] = RRI(m, 0x12b); idx[12] = RRI(m, 0x12c);
    idx[13] = RRI(m, 0x12d); idx[14] = RRI(m, 0x12e); idx[15] = RRI(m, 0x12f);

    float K1[16], K2R[16], sv[16];
#pragma unroll
    for (int j = 0; j < 16; j++) {
        K1[j] = __expf((S[m * 64 + g * 16 + idx[j]] - 1.0f) * 20.0f);
        const float s_ = S[idx[j] * 64 + lane];
        sv[j]  = s_;
        K2R[j] = __expf((s_ - 1.0f) * 20.0f);
    }

    const float muP = 0.0625f + 1e-8f;
    const float nuP = 0.015625f + 1e-8f;
    float b = 1.0f;
    float aB[16], bB[16];
#pragma unroll
    for (int j = 0; j < 16; j++) bB[j] = 1.0f;

#pragma unroll 1
    for (int it = 0; it < 100; it++) {
        float s0 = 0, s1 = 0, s2 = 0, s3 = 0;
#pragma unroll
        for (int j = 0; j < 4; j++) {
            s0 = fmaf(K1[j],      bB[j],      s0);
            s1 = fmaf(K1[4 + j],  bB[4 + j],  s1);
            s2 = fmaf(K1[8 + j],  bB[8 + j],  s2);
            s3 = fmaf(K1[12 + j], bB[12 + j], s3);
        }
        float s = (s0 + s1) + (s2 + s3);
        s = xadd16(s);
        s = xadd32(s);
        const float a = muP * fastrcp(s);
        GATH16(aB, a);
        float t0 = 0, t1 = 0, t2 = 0, t3 = 0;
#pragma unroll
        for (int j = 0; j < 4; j++) {
            t0 = fmaf(K2R[j],      aB[j],      t0);
            t1 = fmaf(K2R[4 + j],  aB[4 + j],  t1);
            t2 = fmaf(K2R[8 + j],  aB[8 + j],  t2);
            t3 = fmaf(K2R[12 + j], aB[12 + j], t3);
        }
        const float bp_ = b;
        b = nuP * fastrcp((t0 + t1) + (t2 + t3));
        GATH16(bB, b);
        const int conv = __builtin_fabsf(b - bp_) <= 1e-5f * __builtin_fabsf(b);
        if (__all(conv)) break;
    }

    float* Sc = score + (long)bk * 1024;
    unsigned short* Tp = Tt + (long)(bk >> 8) * 262144 + (bk & 255);
#pragma unroll
    for (int j = 0; j < 16; j++) {
        const int row = idx[j];
        const float Tv = aB[j] * K2R[j] * b;
        Sc[row * 64 + lane] = 1024.0f * sv[j] * Tv;
        Tp[(long)(row * 64 + lane) * 256] = f2bf(Tv);
    }
}

extern "C" void kernel_launch(void* const* d_in, const int* in_sizes, int n_in,
                              void* d_out, int out_size, void* d_ws, size_t ws_size,
                              hipStream_t stream)
{
    (void)in_sizes; (void)n_in; (void)out_size; (void)ws_size;
    const float* xq = (const float*)d_in[0];
    const float* xk = (const float*)d_in[1];
    const float* xv = (const float*)d_in[2];
    const float* Wq = (const float*)d_in[3];
    const float* Wk = (const float*)d_in[4];
    const float* Wv = (const float*)d_in[5];
    const float* Wp = (const float*)d_in[6];
    const float* bp = (const float*)d_in[7];

    float* out_x     = (float*)d_out;           // (Nq,M,B,C) = 8192 x 512
    float* out_score = out_x + 8192L * 512;     // (B,K,M,Nq) = 2048 x 1024

    // workspace (47 MB of the proven 48 MB); regions reused across phases
    char* W = (char*)d_ws;
    const long MB = 1 << 20;
    unsigned short* qh   = (unsigned short*)(W + 0);        // 8MB [b][mn][c]
    unsigned short* ql   = (unsigned short*)(W + 8 * MB);   // 8MB
    unsigned short* xq_h = (unsigned short*)(W + 16 * MB);  // 8MB, dead after qkv
    float*          simb = (float*)(W + 16 * MB);           // 8MB (reuse)
    unsigned short* xq_l = (unsigned short*)(W + 24 * MB);  // 8MB, dead after qkv
    unsigned short* xpre = (unsigned short*)(W + 24 * MB);  // 8MB (reuse)
    unsigned short* xk_h = (unsigned short*)(W + 32 * MB);  // 2MB, dead after qkv
    unsigned short* xk_l = (unsigned short*)(W + 34 * MB);  // 2MB
    unsigned short* Tt   = (unsigned short*)(W + 32 * MB);  // 4MB (reuse)
    unsigned short* xv_b = (unsigned short*)(W + 36 * MB);  // 2MB
    unsigned short* kh   = (unsigned short*)(W + 38 * MB);  // 2MB [b][k'][c]
    unsigned short* kl   = (unsigned short*)(W + 40 * MB);  // 2MB
    unsigned short* vt   = (unsigned short*)(W + 42 * MB);  // 2MB [b][c][k']
    unsigned short* wqh  = (unsigned short*)(W + 44 * MB);
    unsigned short* wql  = (unsigned short*)(W + 44 * MB + 1 * 524288);
    unsigned short* wkh  = (unsigned short*)(W + 44 * MB + 2 * 524288);
    unsigned short* wkl  = (unsigned short*)(W + 44 * MB + 3 * 524288);
    unsigned short* wvb  = (unsigned short*)(W + 44 * MB + 4 * 524288);
    unsigned short* wpb  = (unsigned short*)(W + 44 * MB + 5 * 524288);

    const dim3 blk(256);

    // 1: precast/split all fp32 operands (memory-bound, one dispatch)
    prep<<<7168, blk, 0, stream>>>(xq, xk, xv, Wq, Wk, Wv, Wp,
                                   xq_h, xq_l, xk_h, xk_l, xv_b,
                                   wqh, wql, wkh, wkl, wvb, wpb);

    // 2: fused q/k/v projections (64x128 tiles, 768 blocks = 3/CU, gll_lds dbuf)
    gemm_qkv2<<<dim3(192, 4), blk, 0, stream>>>(
        xq_h, xq_l, xk_h, xk_l, xv_b, wqh, wql, wkh, wkl, wvb,
        qh, ql, kh, kl, vt);

    // 3: sim[b][k'][mn] = (k.q) * rs_k * rs_q  (norms fused in-kernel)
    gemm_sim64<<<dim3(4, 16, 8), blk, 0, stream>>>(
        (const short*)kh, (const short*)kl, (const short*)qh, (const short*)ql,
        simb);

    // 4: Sinkhorn -> score (out) + T bf16 [b][mn][k']
    sinkhorn5<<<512, blk, 0, stream>>>(simb, out_score, Tt);

    // 5: xpre[b][mn][c] = sum_k' T[b][mn][k'] * v[b][k'][c]
    gemm_bf16<false, false, true><<<dim3(8, 4, 8), blk, 0, stream>>>(
        (const short*)Tt, (const short*)vt, nullptr, xpre,
        256, 256, 256, 512, 262144, 131072, 524288);

    // 6: x = xpre @ Wp^T + bp, rows (b,mn)->(n,m,b), fp32 out
    gemm_bf16<true, true, false><<<dim3(64, 4), blk, 0, stream>>>(
        (const short*)xpre, (const short*)wpb, bp, out_x,
        512, 512, 512, 512, 0, 0, 0);
}

// Round 7
// 180.432 us; speedup vs baseline: 1.1091x; 1.0355x over previous
//
#include <hip/hip_runtime.h>

// ---------------------------------------------------------------------------
// AttentionOT  (Nq=64, M=16, B=8, K=256, C=512)
//   Front (error-critical, feeds exp(20*sim)): bf16x3 split MFMA (Markidis),
//     operands PRE-SPLIT by a memory-bound prep pass.
//   Back half: plain bf16 MFMA, weights precast.
//   Sinkhorn (round 6): launch_bounds(256,2), permlane16/32 butterflies,
//     fixed-point early exit.
//   qkv GEMM (rounds 10-11, verified): 64x128 tiles, gll_lds width-16 dbuf,
//     issue-early/drain-late 2-phase, 768 blocks = 3/CU.
//   rownorm fused into sim64 (round 11, verified).
//   Back GEMMs (round 12): T@V and proj were still naive reg-staged
//     single-buffer at 256 blocks = 1 block/CU (the round-0 qkv pathology).
//     Ported to the same proven 64x128 gll_lds dbuf schedule at 512 blocks
//     = 2/CU each.
//   6 dispatches: prep -> qkv -> sim -> sinkhorn -> T@V -> proj.
// ---------------------------------------------------------------------------

typedef short   short8  __attribute__((ext_vector_type(8)));
typedef float   floatx4 __attribute__((ext_vector_type(4)));
typedef unsigned int uint2e __attribute__((ext_vector_type(2)));

static __device__ __forceinline__ float fastrcp(float x) {
    return __builtin_amdgcn_rcpf(x);
}
static __device__ __forceinline__ unsigned short f2bf(float f) {
    union { float f; unsigned u; } c; c.f = f;
    unsigned r = c.u + 0x7FFF + ((c.u >> 16) & 1);   // RNE
    return (unsigned short)(r >> 16);
}
static __device__ __forceinline__ float bf2f(unsigned short h) {
    union { unsigned u; float f; } c; c.u = (unsigned)h << 16;
    return c.f;
}

// HBM -> LDS direct DMA, 16B per lane. LDS dest is wave-uniform base;
// HW writes lane i at base + i*16 (m03/m97/m104).
static __device__ __forceinline__ void gll16(const unsigned short* g, short* l) {
    __builtin_amdgcn_global_load_lds(
        (const __attribute__((address_space(1))) void*)g,
        (__attribute__((address_space(3))) void*)l, 16, 0, 0);
}

// Cross-lane butterfly adds via gfx950 permlane16/32_swap.
#if __has_builtin(__builtin_amdgcn_permlane16_swap)
static __device__ __forceinline__ float xadd16(float s) {
    uint2e r = __builtin_amdgcn_permlane16_swap(
        __float_as_uint(s), __float_as_uint(s), false, false);
    return __uint_as_float(r.x) + __uint_as_float(r.y);
}
#else
static __device__ __forceinline__ float xadd16(float s) {
    return s + __shfl_xor(s, 16, 64);
}
#endif
#if __has_builtin(__builtin_amdgcn_permlane32_swap)
static __device__ __forceinline__ float xadd32(float s) {
    uint2e r = __builtin_amdgcn_permlane32_swap(
        __float_as_uint(s), __float_as_uint(s), false, false);
    return __uint_as_float(r.x) + __uint_as_float(r.y);
}
#else
static __device__ __forceinline__ float xadd32(float s) {
    return s + __shfl_xor(s, 32, 64);
}
#endif

#define RRI(x, C) __builtin_amdgcn_update_dpp(0, (x), (C), 0xf, 0xf, true)
#define RRF(x, C) __int_as_float(RRI(__float_as_int(x), (C)))
#define GATH16(d, s) do { d[0] = (s);                                        \
    d[1]  = RRF((s), 0x121); d[2]  = RRF((s), 0x122);                        \
    d[3]  = RRF((s), 0x123); d[4]  = RRF((s), 0x124);                        \
    d[5]  = RRF((s), 0x125); d[6]  = RRF((s), 0x126);                        \
    d[7]  = RRF((s), 0x127); d[8]  = RRF((s), 0x128);                        \
    d[9]  = RRF((s), 0x129); d[10] = RRF((s), 0x12a);                        \
    d[11] = RRF((s), 0x12b); d[12] = RRF((s), 0x12c);                        \
    d[13] = RRF((s), 0x12d); d[14] = RRF((s), 0x12e);                        \
    d[15] = RRF((s), 0x12f); } while (0)

// ---------------------------------------------------------------------------
// prep: fp32 -> bf16 split (xq,xk,Wq,Wk) / cast (xv,Wv,Wp).
// ---------------------------------------------------------------------------
__global__ __launch_bounds__(256) void prep(
    const float* __restrict__ xq, const float* __restrict__ xk,
    const float* __restrict__ xv, const float* __restrict__ Wq,
    const float* __restrict__ Wk, const float* __restrict__ Wv,
    const float* __restrict__ Wp,
    unsigned short* __restrict__ xqh, unsigned short* __restrict__ xql,
    unsigned short* __restrict__ xkh, unsigned short* __restrict__ xkl,
    unsigned short* __restrict__ xvb,
    unsigned short* __restrict__ wqh, unsigned short* __restrict__ wql,
    unsigned short* __restrict__ wkh, unsigned short* __restrict__ wkl,
    unsigned short* __restrict__ wvb, unsigned short* __restrict__ wpb)
{
    const int b = blockIdx.x;
    const float* src; unsigned short *dh, *dl; long base;
    if (b < 4096)      { src = xq; dh = xqh; dl = xql;     base = (long)b * 256; }
    else if (b < 5120) { src = xk; dh = xkh; dl = xkl;     base = (long)(b - 4096) * 256; }
    else if (b < 6144) { src = xv; dh = xvb; dl = nullptr; base = (long)(b - 5120) * 256; }
    else if (b < 6400) { src = Wq; dh = wqh; dl = wql;     base = (long)(b - 6144) * 256; }
    else if (b < 6656) { src = Wk; dh = wkh; dl = wkl;     base = (long)(b - 6400) * 256; }
    else if (b < 6912) { src = Wv; dh = wvb; dl = nullptr; base = (long)(b - 6656) * 256; }
    else               { src = Wp; dh = wpb; dl = nullptr; base = (long)(b - 6912) * 256; }
    const long i = base + threadIdx.x;
    float4 v = ((const float4*)src)[i];
    ushort4 h;
    h.x = f2bf(v.x); h.y = f2bf(v.y); h.z = f2bf(v.z); h.w = f2bf(v.w);
    ((ushort4*)dh)[i] = h;
    if (dl) {
        ushort4 l;
        l.x = f2bf(v.x - bf2f(h.x)); l.y = f2bf(v.y - bf2f(h.y));
        l.z = f2bf(v.z - bf2f(h.z)); l.w = f2bf(v.w - bf2f(h.w));
        ((ushort4*)dl)[i] = l;
    }
}

// ---------------------------------------------------------------------------
// Fused q/k/v projection.  64x128 tiles, BK=32, 768 blocks (3/CU).
// gll_lds dbuf 2-phase (verified rounds 10-11).
// ---------------------------------------------------------------------------
__global__ __launch_bounds__(256, 3) void gemm_qkv2(
    const unsigned short* __restrict__ xqh, const unsigned short* __restrict__ xql,
    const unsigned short* __restrict__ xkh, const unsigned short* __restrict__ xkl,
    const unsigned short* __restrict__ xvb,
    const unsigned short* __restrict__ wqh, const unsigned short* __restrict__ wql,
    const unsigned short* __restrict__ wkh, const unsigned short* __restrict__ wkl,
    const unsigned short* __restrict__ wvb,
    unsigned short* __restrict__ qh, unsigned short* __restrict__ ql,
    unsigned short* __restrict__ kh, unsigned short* __restrict__ kl,
    unsigned short* __restrict__ vt)
{
    __shared__ __align__(16) short LB[24576];          // 48 KB (2 x 24KB)

    const int bt = blockIdx.x;
    const unsigned short *Ah, *Al, *Bh, *Bl;
    int seg, arow0;
    if (bt < 128)      { Ah = xqh; Al = xql; Bh = wqh; Bl = wql; arow0 = bt * 64;         seg = 0; }
    else if (bt < 160) { Ah = xkh; Al = xkl; Bh = wkh; Bl = wkl; arow0 = (bt - 128) * 64; seg = 1; }
    else               { Ah = xvb; Al = xvb; Bh = wvb; Bl = wvb; arow0 = (bt - 160) * 64; seg = 2; }
    const bool split = (seg != 2);

    const int tid  = threadIdx.x;
    const int lane = tid & 63, wv = tid >> 6;
    const int wc = wv * 32;                            // wave col slice
    const int j0 = blockIdx.y * 128;

    floatx4 acc[4][2];
#pragma unroll
    for (int i = 0; i < 4; i++)
#pragma unroll
        for (int j = 0; j < 2; j++) acc[i][j] = {0.f, 0.f, 0.f, 0.f};

    const int lrow = lane >> 2;
    const int lch  = (lane & 3) * 8;
    const int gra  = 16 * wv;                          // A wave row base
    const int grb  = 32 * wv;                          // B wave row base
    const long gA0 = (long)(arow0 + gra + lrow) * 512 + lch;
    const long gB0 = (long)(j0    + grb + lrow) * 512 + lch;

    const int fr = lane & 15, fq = (lane >> 4) * 8;

#define QKV_STAGE(d, k0) do {                                                 \
        short* bb = LB + (d) * 12288;                                         \
        gll16(Ah + gA0 + (k0),            bb + gra * 32);                     \
        gll16(Bh + gB0 + (k0),            bb + 4096 + grb * 32);              \
        gll16(Bh + gB0 + (k0) + 16 * 512, bb + 4096 + (grb + 16) * 32);       \
        if (split) {                                                          \
            gll16(Al + gA0 + (k0),            bb + 2048 + gra * 32);          \
            gll16(Bl + gB0 + (k0),            bb + 8192 + grb * 32);          \
            gll16(Bl + gB0 + (k0) + 16 * 512, bb + 8192 + (grb + 16) * 32);   \
        }                                                                     \
    } while (0)

    QKV_STAGE(0, 0);
    __syncthreads();                        // tile 0 ready

#pragma unroll 2
    for (int t = 0; t < 16; t++) {
        const int cur = t & 1;
        if (t < 15) QKV_STAGE(cur ^ 1, (t + 1) * 32);   // issue-early
        const short* base = LB + cur * 12288;
        short8 ah[4], bh[2];
#pragma unroll
        for (int i = 0; i < 4; i++)
            ah[i] = *(const short8*)&base[(i * 16 + fr) * 32 + fq];
#pragma unroll
        for (int j = 0; j < 2; j++)
            bh[j] = *(const short8*)&base[4096 + (wc + j * 16 + fr) * 32 + fq];
        if (split) {
            short8 al[4], bl[2];
#pragma unroll
            for (int i = 0; i < 4; i++)
                al[i] = *(const short8*)&base[2048 + (i * 16 + fr) * 32 + fq];
#pragma unroll
            for (int j = 0; j < 2; j++)
                bl[j] = *(const short8*)&base[8192 + (wc + j * 16 + fr) * 32 + fq];
#pragma unroll
            for (int i = 0; i < 4; i++)
#pragma unroll
                for (int j = 0; j < 2; j++) {
                    acc[i][j] = __builtin_amdgcn_mfma_f32_16x16x32_bf16(ah[i], bh[j], acc[i][j], 0, 0, 0);
                    acc[i][j] = __builtin_amdgcn_mfma_f32_16x16x32_bf16(ah[i], bl[j], acc[i][j], 0, 0, 0);
                    acc[i][j] = __builtin_amdgcn_mfma_f32_16x16x32_bf16(al[i], bh[j], acc[i][j], 0, 0, 0);
                }
        } else {
#pragma unroll
            for (int i = 0; i < 4; i++)
#pragma unroll
                for (int j = 0; j < 2; j++)
                    acc[i][j] = __builtin_amdgcn_mfma_f32_16x16x32_bf16(ah[i], bh[j], acc[i][j], 0, 0, 0);
        }
        __syncthreads();                    // drain-late: vmcnt after compute
    }
#undef QKV_STAGE

    const int cr = (lane >> 4) * 4, cc = lane & 15;
    if (seg == 2) {
        // LDS transpose: S2[c_local][k'_local], rows padded to 72 shorts
        short (*S2)[72] = (short(*)[72])LB;            // 128 x 72 = 18 KB
#pragma unroll
        for (int i = 0; i < 4; i++)
#pragma unroll
            for (int j = 0; j < 2; j++)
#pragma unroll
                for (int r = 0; r < 4; r++)
                    S2[wc + j * 16 + cc][i * 16 + cr + r] =
                        (short)f2bf(acc[i][j][r]);
        __syncthreads();
        const int orow = tid >> 1;            // c_local 0..127
        const int os   = (tid & 1) * 32;      // k'_local chunk
        unsigned short* dst = vt + (long)(arow0 >> 8) * 131072
                            + (long)(j0 + orow) * 256 + (arow0 & 255) + os;
#pragma unroll
        for (int c8 = 0; c8 < 4; c8++)
            *(short8*)(dst + c8 * 8) = *(const short8*)&S2[orow][os + c8 * 8];
    } else {
#pragma unroll
        for (int i = 0; i < 4; i++)
#pragma unroll
            for (int j = 0; j < 2; j++) {
                const int gj = j0 + wc + j * 16 + cc;
#pragma unroll
                for (int r = 0; r < 4; r++) {
                    const int gi = arow0 + i * 16 + cr + r;
                    const float v = acc[i][j][r];
                    const unsigned short h = f2bf(v);
                    const unsigned short lo = f2bf(v - bf2f(h));
                    if (seg == 0) {
                        const long orow = (long)((gi & 7) * 1024 + ((gi >> 3) & 15) * 64 + (gi >> 7));
                        qh[orow * 512 + gj] = h;
                        ql[orow * 512 + gj] = lo;
                    } else {
                        kh[(long)gi * 512 + gj] = h;
                        kl[(long)gi * 512 + gj] = lo;
                    }
                }
            }
    }
}

// ---------------------------------------------------------------------------
// sim GEMM, 64x64 tiles (512 blocks), bf16x3, norms fused in staging.
// ---------------------------------------------------------------------------
__global__ __launch_bounds__(256) void gemm_sim64(
    const short* __restrict__ Ah, const short* __restrict__ Al,
    const short* __restrict__ Bh, const short* __restrict__ Bl,
    float* __restrict__ Out)
{
    const int z = blockIdx.z;
    Ah += (long)z * 131072;  Al += (long)z * 131072;
    Bh += (long)z * 524288;  Bl += (long)z * 524288;
    Out += (long)z * 262144;

    __shared__ __align__(16) short Ash[64][40];
    __shared__ __align__(16) short Asl[64][40];
    __shared__ __align__(16) short Bsh[64][40];
    __shared__ __align__(16) short Bsl[64][40];
    __shared__ float sRA[64];
    __shared__ float sRB[64];

    const int tid  = threadIdx.x;
    const int lane = tid & 63, wv = tid >> 6;
    const int wr = (wv >> 1) * 32, wc = (wv & 1) * 32;
    const int i0 = blockIdx.x * 64, j0 = blockIdx.y * 64;

    floatx4 acc[2][2];
#pragma unroll
    for (int i = 0; i < 2; i++)
#pragma unroll
        for (int j = 0; j < 2; j++) acc[i][j] = {0.f, 0.f, 0.f, 0.f};

    const int sr = tid >> 2, sch = (tid & 3) * 8;
    const int fr = lane & 15, fq = (lane >> 4) * 8;

    float ssqA = 0.0f, ssqB = 0.0f;

    for (int k0 = 0; k0 < 512; k0 += 32) {
        const long ao = (long)(i0 + sr) * 512 + k0 + sch;
        const long bo = (long)(j0 + sr) * 512 + k0 + sch;
        const short8 vah = *(const short8*)(Ah + ao);
        const short8 val_ = *(const short8*)(Al + ao);
        const short8 vbh = *(const short8*)(Bh + bo);
        const short8 vbl = *(const short8*)(Bl + bo);
        *(short8*)&Ash[sr][sch] = vah;
        *(short8*)&Asl[sr][sch] = val_;
        *(short8*)&Bsh[sr][sch] = vbh;
        *(short8*)&Bsl[sr][sch] = vbl;
#pragma unroll
        for (int e = 0; e < 8; e++) {
            const float va = bf2f((unsigned short)vah[e]) + bf2f((unsigned short)val_[e]);
            const float vb = bf2f((unsigned short)vbh[e]) + bf2f((unsigned short)vbl[e]);
            ssqA = fmaf(va, va, ssqA);
            ssqB = fmaf(vb, vb, ssqB);
        }
        __syncthreads();
        short8 ah[2], al[2], bh[2], bl[2];
#pragma unroll
        for (int i = 0; i < 2; i++) {
            ah[i] = *(const short8*)&Ash[wr + i * 16 + fr][fq];
            al[i] = *(const short8*)&Asl[wr + i * 16 + fr][fq];
        }
#pragma unroll
        for (int j = 0; j < 2; j++) {
            bh[j] = *(const short8*)&Bsh[wc + j * 16 + fr][fq];
            bl[j] = *(const short8*)&Bsl[wc + j * 16 + fr][fq];
        }
#pragma unroll
        for (int i = 0; i < 2; i++)
#pragma unroll
            for (int j = 0; j < 2; j++) {
                acc[i][j] = __builtin_amdgcn_mfma_f32_16x16x32_bf16(ah[i], bh[j], acc[i][j], 0, 0, 0);
                acc[i][j] = __builtin_amdgcn_mfma_f32_16x16x32_bf16(ah[i], bl[j], acc[i][j], 0, 0, 0);
                acc[i][j] = __builtin_amdgcn_mfma_f32_16x16x32_bf16(al[i], bh[j], acc[i][j], 0, 0, 0);
            }
        __syncthreads();
    }

    ssqA += __shfl_xor(ssqA, 1, 64);  ssqA += __shfl_xor(ssqA, 2, 64);
    ssqB += __shfl_xor(ssqB, 1, 64);  ssqB += __shfl_xor(ssqB, 2, 64);
    if ((tid & 3) == 0) {
        sRA[sr] = 1.0f / fmaxf(sqrtf(ssqA), 1e-12f);
        sRB[sr] = 1.0f / fmaxf(sqrtf(ssqB), 1e-12f);
    }
    __syncthreads();

    const int cr = (lane >> 4) * 4, cc = lane & 15;
#pragma unroll
    for (int i = 0; i < 2; i++)
#pragma unroll
        for (int j = 0; j < 2; j++) {
            const int lc = wc + j * 16 + cc;
            const float sq = sRB[lc];
            const int gj = j0 + lc;
#pragma unroll
            for (int r = 0; r < 4; r++) {
                const int lr = wr + i * 16 + cr + r;
                Out[(long)(i0 + lr) * 1024 + gj] = acc[i][j][r] * sRA[lr] * sq;
            }
        }
}

// ---------------------------------------------------------------------------
// Plain bf16 MFMA GEMM v2 (T@V and final proj): 64x128 tiles, BK=32,
// gll_lds width-16 dbuf, issue-early/drain-late 2-phase (proven schedule).
// Grid: (i_tiles, j_tiles, batch); 512 blocks = 2/CU for both uses.
// Per buffer (shorts): A[64][32]@0 (2048), B[128][32]@2048 (4096) = 12 KB.
// ---------------------------------------------------------------------------
template <bool BIAS, bool OPERM, bool OUT_BF16>
__global__ __launch_bounds__(256, 2) void gemm_bf16_v2(
    const unsigned short* __restrict__ A, const unsigned short* __restrict__ B,
    const float* __restrict__ bias, void* __restrict__ OutV,
    int Kdim, int lda, int ldb, int ldo, long sA, long sB, long sO)
{
    __shared__ __align__(16) short LB[12288];          // 24 KB (2 x 12KB)

    const int tid  = threadIdx.x;
    const int lane = tid & 63, wv = tid >> 6;
    const int wc = wv * 32;
    const int i0 = blockIdx.x * 64, j0 = blockIdx.y * 128;

    floatx4 acc[4][2];
#pragma unroll
    for (int i = 0; i < 4; i++)
#pragma unroll
        for (int j = 0; j < 2; j++) acc[i][j] = {0.f, 0.f, 0.f, 0.f};

    const unsigned short* pa = A + (long)blockIdx.z * sA;
    const unsigned short* pb = B + (long)blockIdx.z * sB;

    const int lrow = lane >> 2;
    const int lch  = (lane & 3) * 8;
    const int gra  = 16 * wv;                          // A wave row base
    const int grb  = 32 * wv;                          // B wave row base
    const long gA0 = (long)(i0 + gra + lrow) * lda + lch;
    const long gB0 = (long)(j0 + grb + lrow) * ldb + lch;

    const int fr = lane & 15, fq = (lane >> 4) * 8;

#define BF2_STAGE(d, k0) do {                                                 \
        short* bb = LB + (d) * 6144;                                          \
        gll16(pa + gA0 + (k0),             bb + gra * 32);                    \
        gll16(pb + gB0 + (k0),             bb + 2048 + grb * 32);             \
        gll16(pb + gB0 + (k0) + 16 * ldb,  bb + 2048 + (grb + 16) * 32);      \
    } while (0)

    const int nt = Kdim >> 5;
    BF2_STAGE(0, 0);
    __syncthreads();

#pragma unroll 2
    for (int t = 0; t < nt; t++) {
        const int cur = t & 1;
        if (t < nt - 1) BF2_STAGE(cur ^ 1, (t + 1) * 32);   // issue-early
        const short* base = LB + cur * 6144;
        short8 af[4], bf[2];
#pragma unroll
        for (int i = 0; i < 4; i++)
            af[i] = *(const short8*)&base[(i * 16 + fr) * 32 + fq];
#pragma unroll
        for (int j = 0; j < 2; j++)
            bf[j] = *(const short8*)&base[2048 + (wc + j * 16 + fr) * 32 + fq];
#pragma unroll
        for (int i = 0; i < 4; i++)
#pragma unroll
            for (int j = 0; j < 2; j++)
                acc[i][j] = __builtin_amdgcn_mfma_f32_16x16x32_bf16(af[i], bf[j], acc[i][j], 0, 0, 0);
        __syncthreads();                    // drain-late
    }
#undef BF2_STAGE

    float* Of = nullptr; unsigned short* Ob = nullptr;
    if constexpr (OUT_BF16) Ob = (unsigned short*)OutV + (long)blockIdx.z * sO;
    else                    Of = (float*)OutV + (long)blockIdx.z * sO;
    const int cr = (lane >> 4) * 4, cc = lane & 15;
#pragma unroll
    for (int i = 0; i < 4; i++) {
#pragma unroll
        for (int j = 0; j < 2; j++) {
            const int gj = j0 + wc + j * 16 + cc;
            float bb = 0.0f;
            if constexpr (BIAS) bb = bias[gj];
#pragma unroll
            for (int r = 0; r < 4; r++) {
                const int gi = i0 + i * 16 + cr + r;
                float v = acc[i][j][r] + bb;
                long idx;
                if constexpr (OPERM)
                    idx = (long)((gi & 63) * 128 + ((gi >> 6) & 15) * 8 + (gi >> 10)) * ldo + gj;
                else
                    idx = (long)gi * ldo + gj;
                if constexpr (OUT_BF16) Ob[idx] = f2bf(v);
                else                    Of[idx] = v;
            }
        }
    }
}

// ---------------------------------------------------------------------------
// Sinkhorn, rotated dual layouts + DPP + permlane butterflies + early exit.
// ---------------------------------------------------------------------------
__global__ __launch_bounds__(256, 2) void sinkhorn5(
    const float* __restrict__ sim, float* __restrict__ score,
    unsigned short* __restrict__ Tt)
{
    const int lane = threadIdx.x & 63;
    const int bk   = blockIdx.x * 4 + (threadIdx.x >> 6);
    const float* S = sim + (long)bk * 1024;
    const int m = lane & 15, g = lane >> 4;

    int idx[16];
    idx[0] = m;
    idx[1]  = RRI(m, 0x121); idx[2]  = RRI(m, 0x122); idx[3]  = RRI(m, 0x123);
    idx[4]  = RRI(m, 0x124); idx[5]  = RRI(m, 0x125); idx[6]  = RRI(m, 0x126);
    idx[7]  = RRI(m, 0x127); idx[8]  = RRI(m, 0x128); idx[9]  = RRI(m, 0x129);
    idx[10] = RRI(m, 0x12a); idx[11] = RRI(m, 0x12b); idx[12] = RRI(m, 0x12c);
    idx[13] = RRI(m, 0x12d); idx[14] = RRI(m, 0x12e); idx[15] = RRI(m, 0x12f);

    float K1[16], K2R[16], sv[16];
#pragma unroll
    for (int j = 0; j < 16; j++) {
        K1[j] = __expf((S[m * 64 + g * 16 + idx[j]] - 1.0f) * 20.0f);
        const float s_ = S[idx[j] * 64 + lane];
        sv[j]  = s_;
        K2R[j] = __expf((s_ - 1.0f) * 20.0f);
    }

    const float muP = 0.0625f + 1e-8f;
    const float nuP = 0.015625f + 1e-8f;
    float b = 1.0f;
    float aB[16], bB[16];
#pragma unroll
    for (int j = 0; j < 16; j++) bB[j] = 1.0f;

#pragma unroll 1
    for (int it = 0; it < 100; it++) {
        float s0 = 0, s1 = 0, s2 = 0, s3 = 0;
#pragma unroll
        for (int j = 0; j < 4; j++) {
            s0 = fmaf(K1[j],      bB[j],      s0);
            s1 = fmaf(K1[4 + j],  bB[4 + j],  s1);
            s2 = fmaf(K1[8 + j],  bB[8 + j],  s2);
            s3 = fmaf(K1[12 + j], bB[12 + j], s3);
        }
        float s = (s0 + s1) + (s2 + s3);
        s = xadd16(s);
        s = xadd32(s);
        const float a = muP * fastrcp(s);
        GATH16(aB, a);
        float t0 = 0, t1 = 0, t2 = 0, t3 = 0;
#pragma unroll
        for (int j = 0; j < 4; j++) {
            t0 = fmaf(K2R[j],      aB[j],      t0);
            t1 = fmaf(K2R[4 + j],  aB[4 + j],  t1);
            t2 = fmaf(K2R[8 + j],  aB[8 + j],  t2);
            t3 = fmaf(K2R[12 + j], aB[12 + j], t3);
        }
        const float bp_ = b;
        b = nuP * fastrcp((t0 + t1) + (t2 + t3));
        GATH16(bB, b);
        const int conv = __builtin_fabsf(b - bp_) <= 1e-5f * __builtin_fabsf(b);
        if (__all(conv)) break;
    }

    float* Sc = score + (long)bk * 1024;
    unsigned short* Tp = Tt + (long)(bk >> 8) * 262144 + (bk & 255);
#pragma unroll
    for (int j = 0; j < 16; j++) {
        const int row = idx[j];
        const float Tv = aB[j] * K2R[j] * b;
        Sc[row * 64 + lane] = 1024.0f * sv[j] * Tv;
        Tp[(long)(row * 64 + lane) * 256] = f2bf(Tv);
    }
}

extern "C" void kernel_launch(void* const* d_in, const int* in_sizes, int n_in,
                              void* d_out, int out_size, void* d_ws, size_t ws_size,
                              hipStream_t stream)
{
    (void)in_sizes; (void)n_in; (void)out_size; (void)ws_size;
    const float* xq = (const float*)d_in[0];
    const float* xk = (const float*)d_in[1];
    const float* xv = (const float*)d_in[2];
    const float* Wq = (const float*)d_in[3];
    const float* Wk = (const float*)d_in[4];
    const float* Wv = (const float*)d_in[5];
    const float* Wp = (const float*)d_in[6];
    const float* bp = (const float*)d_in[7];

    float* out_x     = (float*)d_out;           // (Nq,M,B,C) = 8192 x 512
    float* out_score = out_x + 8192L * 512;     // (B,K,M,Nq) = 2048 x 1024

    // workspace (47 MB of the proven 48 MB); regions reused across phases
    char* W = (char*)d_ws;
    const long MB = 1 << 20;
    unsigned short* qh   = (unsigned short*)(W + 0);        // 8MB [b][mn][c]
    unsigned short* ql   = (unsigned short*)(W + 8 * MB);   // 8MB
    unsigned short* xq_h = (unsigned short*)(W + 16 * MB);  // 8MB, dead after qkv
    float*          simb = (float*)(W + 16 * MB);           // 8MB (reuse)
    unsigned short* xq_l = (unsigned short*)(W + 24 * MB);  // 8MB, dead after qkv
    unsigned short* xpre = (unsigned short*)(W + 24 * MB);  // 8MB (reuse)
    unsigned short* xk_h = (unsigned short*)(W + 32 * MB);  // 2MB, dead after qkv
    unsigned short* xk_l = (unsigned short*)(W + 34 * MB);  // 2MB
    unsigned short* Tt   = (unsigned short*)(W + 32 * MB);  // 4MB (reuse)
    unsigned short* xv_b = (unsigned short*)(W + 36 * MB);  // 2MB
    unsigned short* kh   = (unsigned short*)(W + 38 * MB);  // 2MB [b][k'][c]
    unsigned short* kl   = (unsigned short*)(W + 40 * MB);  // 2MB
    unsigned short* vt   = (unsigned short*)(W + 42 * MB);  // 2MB [b][c][k']
    unsigned short* wqh  = (unsigned short*)(W + 44 * MB);
    unsigned short* wql  = (unsigned short*)(W + 44 * MB + 1 * 524288);
    unsigned short* wkh  = (unsigned short*)(W + 44 * MB + 2 * 524288);
    unsigned short* wkl  = (unsigned short*)(W + 44 * MB + 3 * 524288);
    unsigned short* wvb  = (unsigned short*)(W + 44 * MB + 4 * 524288);
    unsigned short* wpb  = (unsigned short*)(W + 44 * MB + 5 * 524288);

    const dim3 blk(256);

    // 1: precast/split all fp32 operands (memory-bound, one dispatch)
    prep<<<7168, blk, 0, stream>>>(xq, xk, xv, Wq, Wk, Wv, Wp,
                                   xq_h, xq_l, xk_h, xk_l, xv_b,
                                   wqh, wql, wkh, wkl, wvb, wpb);

    // 2: fused q/k/v projections (64x128 tiles, 768 blocks = 3/CU, gll_lds dbuf)
    gemm_qkv2<<<dim3(192, 4), blk, 0, stream>>>(
        xq_h, xq_l, xk_h, xk_l, xv_b, wqh, wql, wkh, wkl, wvb,
        qh, ql, kh, kl, vt);

    // 3: sim[b][k'][mn] = (k.q) * rs_k * rs_q  (norms fused in-kernel)
    gemm_sim64<<<dim3(4, 16, 8), blk, 0, stream>>>(
        (const short*)kh, (const short*)kl, (const short*)qh, (const short*)ql,
        simb);

    // 4: Sinkhorn -> score (out) + T bf16 [b][mn][k']
    sinkhorn5<<<512, blk, 0, stream>>>(simb, out_score, Tt);

    // 5: xpre[b][mn][c] = sum_k' T[b][mn][k'] * v[b][k'][c]
    //    64x128 tiles: (1024/64, 512/128, 8) = 512 blocks = 2/CU
    gemm_bf16_v2<false, false, true><<<dim3(16, 4, 8), blk, 0, stream>>>(
        Tt, vt, nullptr, xpre,
        256, 256, 256, 512, 262144, 131072, 524288);

    // 6: x = xpre @ Wp^T + bp, rows (b,mn)->(n,m,b), fp32 out
    //    64x128 tiles: (8192/64, 512/128) = 512 blocks = 2/CU
    gemm_bf16_v2<true, true, false><<<dim3(128, 4), blk, 0, stream>>>(
        xpre, wpb, bp, out_x,
        512, 512, 512, 512, 0, 0, 0);
}